// Round 6
// baseline (13847.870 us; speedup 1.0000x reference)
//
#include <hip/hip_runtime.h>
#include <stdint.h>

// ---------------------------------------------------------------------------
// ODE-RNN encoder, f32 I/O, bf16 MFMA internals.
// R6: kill spills by shrinking per-wave state. ode_mega: 1024 threads,
// 16 waves in a 2(M)x8(N) grid -> per-wave acc 32 / h 32 / ks 16 / bb 32
// (~120 live regs, fits the 128-reg allocation the backend insists on).
// B operand stays global->VGPR (per-wave-private, coalesced via tiled
// weights), K-loop barrier-free, epilogue barriers are lgkm-only.
// ---------------------------------------------------------------------------

typedef __bf16 bf16x8 __attribute__((ext_vector_type(8)));
typedef float floatx4 __attribute__((ext_vector_type(4)));

#define BP 40  // gru_step padded B row (ushorts)

static __device__ __forceinline__ float bf2f(unsigned short u) {
  union { unsigned int u32; float f; } c;
  c.u32 = ((unsigned int)u) << 16;
  return c.f;
}
static __device__ __forceinline__ unsigned short f2bf(float f) {
  union { __bf16 h; unsigned short u; } c;
  c.h = (__bf16)f;  // RNE
  return c.u;
}

// LDS-only barrier: does NOT drain vmcnt, so global prefetches stay in flight.
static __device__ __forceinline__ void barrier_lds() {
  __asm__ volatile("s_waitcnt lgkmcnt(0)\n\ts_barrier" ::: "memory");
}

// ---------------------------------------------------------------------------
// tile_weight: W (K=512 x N=512, f32 row-major) -> bf16 tiled
// [kk(16)][nt(32)][qd(4)][ml(16)][8]; element (kk,nt,qd,ml,j) = W[kk*32+qd*8+j][nt*16+ml]
// ---------------------------------------------------------------------------
__global__ void tile_weight(const float* __restrict__ src, unsigned short* __restrict__ dst) {
  int t = blockIdx.x * 256 + threadIdx.x;  // 0..32767
  int ml = t & 15, qd = (t >> 4) & 3;
  int nt = (t >> 6) & 31, kk = t >> 11;
  int n = nt * 16 + ml;
  int k0 = kk * 32 + qd * 8;
  unsigned short o[8] __attribute__((aligned(16)));
#pragma unroll
  for (int j = 0; j < 8; ++j) o[j] = f2bf(src[(size_t)(k0 + j) * 512 + n]);
  *(uint4*)(dst + (size_t)t * 8) = *(const uint4*)o;
}

// ---------------------------------------------------------------------------
// transpose + f32->bf16 (GRU weights, [n][k] flat layout)
// ---------------------------------------------------------------------------
__global__ void transpose_f2b(const float* __restrict__ src, unsigned short* __restrict__ dst,
                              int R, int C) {
  __shared__ float t[32][33];
  int c0 = blockIdx.x * 32, r0 = blockIdx.y * 32;
  int tx = threadIdx.x, ty = threadIdx.y;  // 32 x 8
#pragma unroll
  for (int i = 0; i < 32; i += 8) t[ty + i][tx] = src[(size_t)(r0 + ty + i) * C + c0 + tx];
  __syncthreads();
#pragma unroll
  for (int i = 0; i < 32; i += 8) dst[(size_t)(c0 + ty + i) * R + r0 + tx] = f2bf(t[tx][ty + i]);
}

// ---------------------------------------------------------------------------
// obs embed: y = leaky(LN(xs @ W + b)) (f32 in, bf16 out), one wave per row
// ---------------------------------------------------------------------------
__global__ __launch_bounds__(256) void obs_embed(
    const float* __restrict__ xs, const float* __restrict__ W,
    const float* __restrict__ bias, const float* __restrict__ gam,
    const float* __restrict__ bet, unsigned short* __restrict__ Y) {
  __shared__ float Wl[4096];
  const int tid = threadIdx.x, lane = tid & 63, wv = tid >> 6;
#pragma unroll
  for (int i = 0; i < 16; ++i) Wl[i * 256 + tid] = W[i * 256 + tid];
  __syncthreads();
  size_t row = (size_t)blockIdx.x * 4 + wv;
  float xf[8];
  {
    const float* xp = xs + row * 8;
#pragma unroll
    for (int k = 0; k < 8; ++k) xf[k] = xp[k];
  }
  int n0 = lane * 8;
  float a[8];
#pragma unroll
  for (int j = 0; j < 8; ++j) a[j] = bias[n0 + j];
#pragma unroll
  for (int k = 0; k < 8; ++k)
#pragma unroll
    for (int j = 0; j < 8; ++j) a[j] += xf[k] * Wl[k * 512 + n0 + j];
  float s1 = 0.f, s2 = 0.f;
#pragma unroll
  for (int j = 0; j < 8; ++j) { s1 += a[j]; s2 += a[j] * a[j]; }
#pragma unroll
  for (int off = 1; off < 64; off <<= 1) { s1 += __shfl_xor(s1, off); s2 += __shfl_xor(s2, off); }
  float mean = s1 * (1.f / 512.f);
  float rstd = rsqrtf(s2 * (1.f / 512.f) - mean * mean + 1e-5f);
  unsigned short o[8] __attribute__((aligned(16)));
#pragma unroll
  for (int j = 0; j < 8; ++j) {
    float v = (a[j] - mean) * rstd * gam[n0 + j] + bet[n0 + j];
    v = v > 0.f ? v : 0.01f * v;
    o[j] = f2bf(v);
  }
  *(uint4*)(Y + row * 512 + n0) = *(const uint4*)o;
}

// ---------------------------------------------------------------------------
// ODE megakernel. A (64x512) resident in tiled LDS [mt][kk][qd][ml][8];
// 16 waves: wm = wv>>3 owns M-tiles {2wm, 2wm+1}, wy = wv&7 owns N-tiles
// {4wy..4wy+3}. B fragments stream global->VGPR; K-loop barrier-free.
// ---------------------------------------------------------------------------

// element (row, n) address in tiled A (ushort index)
static __device__ __forceinline__ int a_addr(int row, int n) {
  return (((row >> 4) * 16 + (n >> 5)) * 4 + ((n >> 3) & 3)) * 128 + (row & 15) * 8 + (n & 7);
}

static __device__ __forceinline__ void bload(const unsigned short* __restrict__ Wt, int kk,
                                             int wy, int lane, bf16x8 (&b)[4]) {
#pragma unroll
  for (int ni = 0; ni < 4; ++ni)
    b[ni] = *(const bf16x8*)(Wt + ((size_t)kk * 32 + 4 * wy + ni) * 512 + (size_t)lane * 8);
}

// bb must hold Wt slabs {0,1} on entry; holds Wnext slabs {0,1} on exit.
static __device__ __forceinline__ void gemm64d(const unsigned short* __restrict__ Wt,
                                               const unsigned short* __restrict__ Wnext,
                                               const unsigned short* As, int wm, int wy, int lane,
                                               bf16x8 (&bb)[2][4], floatx4 (&acc)[2][4]) {
#pragma unroll
  for (int mi = 0; mi < 2; ++mi)
#pragma unroll
    for (int ni = 0; ni < 4; ++ni) acc[mi][ni] = 0.f;
#pragma unroll
  for (int kk = 0; kk < 16; ++kk) {
    bf16x8 a[2];
#pragma unroll
    for (int mi = 0; mi < 2; ++mi)
      a[mi] = *(const bf16x8*)&As[((wm * 2 + mi) * 16 + kk) * 512 + lane * 8];
#pragma unroll
    for (int mi = 0; mi < 2; ++mi)
#pragma unroll
      for (int ni = 0; ni < 4; ++ni)
        acc[mi][ni] =
            __builtin_amdgcn_mfma_f32_16x16x32_bf16(a[mi], bb[kk & 1][ni], acc[mi][ni], 0, 0, 0);
    // refill the just-consumed slot: kk+2 of this weight, or next weight's 0/1
    if (kk < 14) bload(Wt, kk + 2, wy, lane, bb[kk & 1]);
    else bload(Wnext, kk - 14, wy, lane, bb[kk & 1]);
  }
}

// LN + leaky epilogue; writes bf16 result into tiled As.
static __device__ __forceinline__ void ln_epi64(floatx4 (&acc)[2][4], unsigned short* As,
                                                const unsigned short* Ps, int pb, int pg, int pbe,
                                                bool addt, float tval, int wm, int wy, int lane,
                                                int tid, float2* red, float* stat) {
  const int ml = lane & 15, qd = lane >> 4;
#pragma unroll
  for (int ni = 0; ni < 4; ++ni) {
    int n = (4 * wy + ni) * 16 + ml;
    float bias = bf2f(Ps[pb * 512 + n]);
    if (addt) bias += tval * bf2f(Ps[512 + n]);
#pragma unroll
    for (int mi = 0; mi < 2; ++mi)
#pragma unroll
      for (int r = 0; r < 4; ++r) acc[mi][ni][r] += bias;
  }
#pragma unroll
  for (int mi = 0; mi < 2; ++mi)
#pragma unroll
    for (int r = 0; r < 4; ++r) {
      float s1 = 0.f, s2 = 0.f;
#pragma unroll
      for (int ni = 0; ni < 4; ++ni) { float x = acc[mi][ni][r]; s1 += x; s2 += x * x; }
#pragma unroll
      for (int off = 1; off < 16; off <<= 1) { s1 += __shfl_xor(s1, off); s2 += __shfl_xor(s2, off); }
      if (ml == 0) red[((wm * 2 + mi) * 16 + 4 * qd + r) * 8 + wy] = make_float2(s1, s2);
    }
  barrier_lds();  // red visible; all waves past their As a-frag reads
  if (tid < 64) {
    float S1 = 0.f, S2 = 0.f;
#pragma unroll
    for (int w = 0; w < 8; ++w) { float2 v = red[tid * 8 + w]; S1 += v.x; S2 += v.y; }
    float mean = S1 * (1.f / 512.f);
    float var = S2 * (1.f / 512.f) - mean * mean;
    stat[tid * 2] = mean;
    stat[tid * 2 + 1] = rsqrtf(var + 1e-5f);
  }
  barrier_lds();
#pragma unroll
  for (int mi = 0; mi < 2; ++mi)
#pragma unroll
    for (int r = 0; r < 4; ++r) {
      int row = (wm * 2 + mi) * 16 + 4 * qd + r;
      float mean = stat[row * 2], rstd = stat[row * 2 + 1];
#pragma unroll
      for (int ni = 0; ni < 4; ++ni) {
        int n = (4 * wy + ni) * 16 + ml;
        float x = (acc[mi][ni][r] - mean) * rstd * bf2f(Ps[pg * 512 + n]) + bf2f(Ps[pbe * 512 + n]);
        x = x > 0.f ? x : 0.01f * x;
        As[a_addr(row, n)] = f2bf(x);
      }
    }
  barrier_lds();  // As writes visible
}

// RK4 stage: k = acc + bout; h fp32, ksum packed bf16 pairs; writes y into As.
static __device__ __forceinline__ void stage_epi64(floatx4 (&acc)[2][4], float (&h)[2][4][4],
                                                   unsigned int (&ks)[2][4][2], unsigned short* As,
                                                   const unsigned short* Ps, int stg, int wm,
                                                   int wy, int lane) {
  const int ml = lane & 15, qd = lane >> 4;
  barrier_lds();  // K-loop has no barriers: ensure all waves done reading As
#pragma unroll
  for (int mi = 0; mi < 2; ++mi)
#pragma unroll
    for (int ni = 0; ni < 4; ++ni) {
      int n = (4 * wy + ni) * 16 + ml;
      float bias = bf2f(Ps[7 * 512 + n]);
#pragma unroll
      for (int rp = 0; rp < 2; ++rp) {
        float kv0 = acc[mi][ni][2 * rp] + bias;
        float kv1 = acc[mi][ni][2 * rp + 1] + bias;
        unsigned int pk = ks[mi][ni][rp];
        float s0 = bf2f((unsigned short)(pk & 0xffffu));
        float s1 = bf2f((unsigned short)(pk >> 16));
        float h0 = h[mi][ni][2 * rp], h1 = h[mi][ni][2 * rp + 1];
        float y0, y1;
        if (stg == 0)      { s0 = kv0;        s1 = kv1;        y0 = h0 + 0.125f * kv0; y1 = h1 + 0.125f * kv1; }
        else if (stg == 1) { s0 += 2.f * kv0; s1 += 2.f * kv1; y0 = h0 + 0.125f * kv0; y1 = h1 + 0.125f * kv1; }
        else if (stg == 2) { s0 += 2.f * kv0; s1 += 2.f * kv1; y0 = h0 + 0.25f * kv0;  y1 = h1 + 0.25f * kv1; }
        else {
          h0 += (1.f / 24.f) * (s0 + kv0);  // dt/6, dt=0.25
          h1 += (1.f / 24.f) * (s1 + kv1);
          h[mi][ni][2 * rp] = h0; h[mi][ni][2 * rp + 1] = h1;
          y0 = h0; y1 = h1;
        }
        ks[mi][ni][rp] = (unsigned int)f2bf(s0) | ((unsigned int)f2bf(s1) << 16);
        int row = (wm * 2 + mi) * 16 + 4 * qd + 2 * rp;
        As[a_addr(row, n)] = f2bf(y0);
        As[a_addr(row + 1, n)] = f2bf(y1);
      }
    }
  barrier_lds();  // As writes visible
}

__global__ __launch_bounds__(1024) __attribute__((amdgpu_waves_per_eu(4, 4))) void ode_mega(
    const unsigned short* Y, const unsigned short* __restrict__ W1t,
    const unsigned short* __restrict__ W2t, const unsigned short* __restrict__ Wot,
    const float* __restrict__ b1, const float* __restrict__ tr, const float* __restrict__ g1,
    const float* __restrict__ be1, const float* __restrict__ b2, const float* __restrict__ g2,
    const float* __restrict__ be2, const float* __restrict__ bo, unsigned short* Yout) {
  __shared__ __align__(16) unsigned short As[32768];  // 64KB tiled A
  __shared__ __align__(16) unsigned short Ps[4096];   // 8 x 512 bf16 params
  __shared__ float2 red[512];                         // 4KB
  __shared__ float stat[128];                         // 512B
  __shared__ float ldspad[1024];                      // 4KB: force 1 block/CU

  const int tid = threadIdx.x;
  const int lane = tid & 63;
  const int wv = tid >> 6;   // 0..15
  const int wm = wv >> 3;    // 0..1  (M half)
  const int wy = wv & 7;     // 0..7  (N eighth)
  const int ml = lane & 15;
  const int qd = lane >> 4;
  const size_t m0 = (size_t)blockIdx.x * 64;
  if (tid == 2047) ldspad[0] = 0.f;  // keep pad alive

  // start weight prefetch immediately
  bf16x8 bb[2][4];
  bload(W1t, 0, wy, lane, bb[0]);
  bload(W1t, 1, wy, lane, bb[1]);

  if (tid < 512) {
    const float* srcs[8] = {b1, tr, g1, be1, b2, g2, be2, bo};
#pragma unroll
    for (int v = 0; v < 8; ++v) Ps[v * 512 + tid] = f2bf(srcs[v][tid]);
  }
  // stage initial A: 4096 chunks of 8 bf16 over 1024 threads
#pragma unroll
  for (int c = 0; c < 4; ++c) {
    int id = c * 1024 + tid;
    int r = id >> 6, kc = id & 63;
    uint4 v = *(const uint4*)(Y + (m0 + r) * 512 + kc * 8);
    int dst = (((r >> 4) * 16 + (kc >> 2)) * 4 + (kc & 3)) * 128 + (r & 15) * 8;
    *(uint4*)(As + dst) = v;
  }
  barrier_lds();

  float h[2][4][4];          // fp32 ODE state, MFMA C-layout
  unsigned int ks[2][4][2];  // RK4 ksum, packed bf16 pairs
#pragma unroll
  for (int mi = 0; mi < 2; ++mi)
#pragma unroll
    for (int ni = 0; ni < 4; ++ni) {
      ks[mi][ni][0] = 0u; ks[mi][ni][1] = 0u;
      int n = (4 * wy + ni) * 16 + ml;
#pragma unroll
      for (int r = 0; r < 4; ++r)
        h[mi][ni][r] = bf2f(As[a_addr((wm * 2 + mi) * 16 + 4 * qd + r, n)]);
    }

  for (int e = 0; e < 16; ++e) {  // 4 RK4 steps x 4 stages
    int stg = e & 3;
    float tval = 0.25f * (float)(e >> 2) + ((stg == 3) ? 0.25f : (stg ? 0.125f : 0.f));
    floatx4 acc[2][4];
    gemm64d(W1t, W2t, As, wm, wy, lane, bb, acc);
    ln_epi64(acc, As, Ps, 0, 2, 3, true, tval, wm, wy, lane, tid, red, stat);
    gemm64d(W2t, Wot, As, wm, wy, lane, bb, acc);
    ln_epi64(acc, As, Ps, 4, 5, 6, false, 0.f, wm, wy, lane, tid, red, stat);
    gemm64d(Wot, W1t, As, wm, wy, lane, bb, acc);  // preloads next eval's W1
    stage_epi64(acc, h, ks, As, Ps, stg, wm, wy, lane);
  }

  // final h_ode (bf16, row-major) for the GRU phase
#pragma unroll
  for (int mi = 0; mi < 2; ++mi)
#pragma unroll
    for (int ni = 0; ni < 4; ++ni)
#pragma unroll
      for (int r = 0; r < 4; ++r) {
        size_t row = m0 + (wm * 2 + mi) * 16 + 4 * qd + r;
        int n = (4 * wy + ni) * 16 + ml;
        Yout[row * 512 + n] = f2bf(h[mi][ni][r]);
      }
}

// ---------------------------------------------------------------------------
// GRU step (unchanged): gi = y_t @ W_ih, gh = h_prev @ W_hh, gates.
// grid (32, 8): 32 rows x 64 gate-cols per block, 4 waves.
// ---------------------------------------------------------------------------
__global__ __launch_bounds__(256) void gru_step(
    const unsigned short* __restrict__ Yt, const float* __restrict__ hprev,
    float* __restrict__ hnew, const unsigned short* __restrict__ Wiht,
    const unsigned short* __restrict__ Whht, const float* __restrict__ bih,
    const float* __restrict__ bhh) {
  __shared__ __align__(16) unsigned short Ay[32 * BP];
  __shared__ __align__(16) unsigned short Ah[32 * BP];
  __shared__ __align__(16) unsigned short Bg[6 * 64 * BP];
  const int tid = threadIdx.x, lane = tid & 63, wv = tid >> 6;
  const int ml = lane & 15, qd = lane >> 4;
  const int m0 = blockIdx.x * 32;
  const int j0 = blockIdx.y * 64;

  floatx4 acc[2][6];
#pragma unroll
  for (int mi = 0; mi < 2; ++mi)
#pragma unroll
    for (int g = 0; g < 6; ++g) acc[mi][g] = 0.f;

  for (int kk = 0; kk < 16; ++kk) {
    __syncthreads();
#pragma unroll
    for (int c = 0; c < 7; ++c) {
      int id = c * 256 + tid;
      if (id < 128) {
        int r = id >> 2, kc = id & 3;
        *(uint4*)(Ay + r * BP + kc * 8) =
            *(const uint4*)(Yt + (size_t)(m0 + r) * 512 + kk * 32 + kc * 8);
      } else if (id < 256) {
        int id2 = id - 128;
        int r = id2 >> 2, kc = id2 & 3;
        const float* s = hprev + (size_t)(m0 + r) * 512 + kk * 32 + kc * 8;
        unsigned short o[8] __attribute__((aligned(16)));
#pragma unroll
        for (int j = 0; j < 8; ++j) o[j] = f2bf(s[j]);
        *(uint4*)(Ah + r * BP + kc * 8) = *(const uint4*)o;
      } else {
        int id2 = id - 256;
        int g = id2 >> 8;
        int rem = id2 & 255;
        int r = rem >> 2, kc = rem & 3;
        const unsigned short* mat = (g < 3) ? Wiht : Whht;
        int gate = (g < 3) ? g : (g - 3);
        *(uint4*)(Bg + g * (64 * BP) + r * BP + kc * 8) =
            *(const uint4*)(mat + (size_t)(gate * 512 + j0 + r) * 512 + kk * 32 + kc * 8);
      }
    }
    __syncthreads();
    bf16x8 ay[2], ah[2];
#pragma unroll
    for (int mi = 0; mi < 2; ++mi) {
      ay[mi] = *(const bf16x8*)&Ay[(16 * mi + ml) * BP + qd * 8];
      ah[mi] = *(const bf16x8*)&Ah[(16 * mi + ml) * BP + qd * 8];
    }
#pragma unroll
    for (int g = 0; g < 6; ++g) {
      bf16x8 b = *(const bf16x8*)&Bg[g * (64 * BP) + (16 * wv + ml) * BP + qd * 8];
#pragma unroll
      for (int mi = 0; mi < 2; ++mi)
        acc[mi][g] = __builtin_amdgcn_mfma_f32_16x16x32_bf16((g < 3) ? ay[mi] : ah[mi], b,
                                                             acc[mi][g], 0, 0, 0);
    }
  }
  int j = j0 + 16 * wv + ml;
  float bi_r = bih[j], bi_z = bih[512 + j], bi_n = bih[1024 + j];
  float bh_r = bhh[j], bh_z = bhh[512 + j], bh_n = bhh[1024 + j];
#pragma unroll
  for (int mi = 0; mi < 2; ++mi)
#pragma unroll
    for (int r = 0; r < 4; ++r) {
      size_t row = (size_t)(m0 + 16 * mi + 4 * qd + r);
      float rg = acc[mi][0][r] + bi_r + acc[mi][3][r] + bh_r;
      rg = 1.f / (1.f + __expf(-rg));
      float zg = acc[mi][1][r] + bi_z + acc[mi][4][r] + bh_z;
      zg = 1.f / (1.f + __expf(-zg));
      float ng = tanhf(acc[mi][2][r] + bi_n + rg * (acc[mi][5][r] + bh_n));
      float hp = hprev[row * 512 + j];
      hnew[row * 512 + j] = (1.f - zg) * ng + zg * hp;
    }
}

__global__ void zero_h(float* hf) {
  int i = blockIdx.x * 256 + threadIdx.x;
  hf[i] = 0.f;
}

// ---------------------------------------------------------------------------
extern "C" void kernel_launch(void* const* d_in, const int* in_sizes, int n_in,
                              void* d_out, int out_size, void* d_ws, size_t ws_size,
                              hipStream_t stream) {
  (void)in_sizes; (void)n_in; (void)out_size; (void)ws_size;
  const float* xs    = (const float*)d_in[0];
  const float* obsW  = (const float*)d_in[1];
  const float* obsb  = (const float*)d_in[2];
  const float* obsg  = (const float*)d_in[3];
  const float* obsbe = (const float*)d_in[4];
  const float* W1    = (const float*)d_in[5];
  const float* b1    = (const float*)d_in[6];
  const float* g1    = (const float*)d_in[7];
  const float* be1   = (const float*)d_in[8];
  const float* W2    = (const float*)d_in[9];
  const float* b2    = (const float*)d_in[10];
  const float* g2    = (const float*)d_in[11];
  const float* be2   = (const float*)d_in[12];
  const float* Wo    = (const float*)d_in[13];
  const float* bo    = (const float*)d_in[14];
  const float* Wih   = (const float*)d_in[15];
  const float* bih   = (const float*)d_in[16];
  const float* Whh   = (const float*)d_in[17];
  const float* bhh   = (const float*)d_in[18];

  char* p = (char*)d_ws;
  auto take = [&](size_t bytes) { char* q = p; p += (bytes + 255) & ~(size_t)255; return q; };
  unsigned short* W1t  = (unsigned short*)take((size_t)512 * 512 * 2);
  unsigned short* W2t  = (unsigned short*)take((size_t)512 * 512 * 2);
  unsigned short* Wot  = (unsigned short*)take((size_t)512 * 512 * 2);
  unsigned short* Wiht = (unsigned short*)take((size_t)1536 * 512 * 2);
  unsigned short* Whht = (unsigned short*)take((size_t)1536 * 512 * 2);
  float* hf0 = (float*)take((size_t)1024 * 512 * 4);
  float* hf1 = (float*)take((size_t)1024 * 512 * 4);
  unsigned short* Yb = (unsigned short*)take((size_t)65536 * 512 * 2);

  dim3 tb(32, 8);
  tile_weight<<<128, 256, 0, stream>>>(W1, W1t);  // first 512 of 513 rows
  tile_weight<<<128, 256, 0, stream>>>(W2, W2t);
  tile_weight<<<128, 256, 0, stream>>>(Wo, Wot);
  transpose_f2b<<<dim3(48, 16), tb, 0, stream>>>(Wih, Wiht, 512, 1536);
  transpose_f2b<<<dim3(48, 16), tb, 0, stream>>>(Whh, Whht, 512, 1536);

  obs_embed<<<16384, 256, 0, stream>>>(xs, obsW, obsb, obsg, obsbe, Yb);

  // tr = W1 row 512 (time row), folded into layer-1 bias per eval.
  ode_mega<<<1024, 1024, 0, stream>>>(Yb, W1t, W2t, Wot, b1, W1 + 512 * 512, g1, be1, b2, g2,
                                      be2, bo, Yb);

  zero_h<<<2048, 256, 0, stream>>>(hf0);
  float* hf[2] = {hf0, hf1};
  for (int t = 0; t < 64; ++t) {
    int s = t & 1, d = s ^ 1;
    float* hn = (t == 63) ? (float*)d_out : hf[d];
    gru_step<<<dim3(32, 8), 256, 0, stream>>>(Yb + (size_t)t * 1024 * 512, hf[s], hn, Wiht, Whht,
                                              bih, bhh);
  }
}

// Round 7
// 7530.251 us; speedup vs baseline: 1.8390x; 1.8390x over previous
//
#include <hip/hip_runtime.h>
#include <stdint.h>

// ---------------------------------------------------------------------------
// ODE-RNN encoder, f32 I/O, bf16 MFMA internals.
// R7 = R5 structure + LDS forced >80KB so only 1 block/CU fits; the VGPR
// allocator then targets 2 waves/EU -> 256-reg budget -> no spills.
// (R4-R6 evidence: with 76.5KB LDS it targets 2 blocks/CU and caps at
// 128/64 regs, spilling ~3-4GB to scratch; attributes don't override.)
// B operand: global->VGPR per-wave (coalesced via tiled weights), K-loop
// barrier-free, epilogue barriers lgkm-only so prefetches stay in flight.
// ---------------------------------------------------------------------------

typedef __bf16 bf16x8 __attribute__((ext_vector_type(8)));
typedef float floatx4 __attribute__((ext_vector_type(4)));

#define BP 40  // gru_step padded B row (ushorts)

static __device__ __forceinline__ float bf2f(unsigned short u) {
  union { unsigned int u32; float f; } c;
  c.u32 = ((unsigned int)u) << 16;
  return c.f;
}
static __device__ __forceinline__ unsigned short f2bf(float f) {
  union { __bf16 h; unsigned short u; } c;
  c.h = (__bf16)f;  // RNE
  return c.u;
}

// LDS-only barrier: does NOT drain vmcnt, so global prefetches stay in flight.
static __device__ __forceinline__ void barrier_lds() {
  __asm__ volatile("s_waitcnt lgkmcnt(0)\n\ts_barrier" ::: "memory");
}

// ---------------------------------------------------------------------------
// tile_weight: W (K=512 x N=512, f32 row-major) -> bf16 tiled
// [kk(16)][nt(32)][qd(4)][ml(16)][8]; element (kk,nt,qd,ml,j) = W[kk*32+qd*8+j][nt*16+ml]
// ---------------------------------------------------------------------------
__global__ void tile_weight(const float* __restrict__ src, unsigned short* __restrict__ dst) {
  int t = blockIdx.x * 256 + threadIdx.x;  // 0..32767
  int ml = t & 15, qd = (t >> 4) & 3;
  int nt = (t >> 6) & 31, kk = t >> 11;
  int n = nt * 16 + ml;
  int k0 = kk * 32 + qd * 8;
  unsigned short o[8] __attribute__((aligned(16)));
#pragma unroll
  for (int j = 0; j < 8; ++j) o[j] = f2bf(src[(size_t)(k0 + j) * 512 + n]);
  *(uint4*)(dst + (size_t)t * 8) = *(const uint4*)o;
}

// ---------------------------------------------------------------------------
// transpose + f32->bf16 (GRU weights, [n][k] flat layout)
// ---------------------------------------------------------------------------
__global__ void transpose_f2b(const float* __restrict__ src, unsigned short* __restrict__ dst,
                              int R, int C) {
  __shared__ float t[32][33];
  int c0 = blockIdx.x * 32, r0 = blockIdx.y * 32;
  int tx = threadIdx.x, ty = threadIdx.y;  // 32 x 8
#pragma unroll
  for (int i = 0; i < 32; i += 8) t[ty + i][tx] = src[(size_t)(r0 + ty + i) * C + c0 + tx];
  __syncthreads();
#pragma unroll
  for (int i = 0; i < 32; i += 8) dst[(size_t)(c0 + ty + i) * R + r0 + tx] = f2bf(t[tx][ty + i]);
}

// ---------------------------------------------------------------------------
// obs embed: y = leaky(LN(xs @ W + b)) (f32 in, bf16 out), one wave per row
// ---------------------------------------------------------------------------
__global__ __launch_bounds__(256) void obs_embed(
    const float* __restrict__ xs, const float* __restrict__ W,
    const float* __restrict__ bias, const float* __restrict__ gam,
    const float* __restrict__ bet, unsigned short* __restrict__ Y) {
  __shared__ float Wl[4096];
  const int tid = threadIdx.x, lane = tid & 63, wv = tid >> 6;
#pragma unroll
  for (int i = 0; i < 16; ++i) Wl[i * 256 + tid] = W[i * 256 + tid];
  __syncthreads();
  size_t row = (size_t)blockIdx.x * 4 + wv;
  float xf[8];
  {
    const float* xp = xs + row * 8;
#pragma unroll
    for (int k = 0; k < 8; ++k) xf[k] = xp[k];
  }
  int n0 = lane * 8;
  float a[8];
#pragma unroll
  for (int j = 0; j < 8; ++j) a[j] = bias[n0 + j];
#pragma unroll
  for (int k = 0; k < 8; ++k)
#pragma unroll
    for (int j = 0; j < 8; ++j) a[j] += xf[k] * Wl[k * 512 + n0 + j];
  float s1 = 0.f, s2 = 0.f;
#pragma unroll
  for (int j = 0; j < 8; ++j) { s1 += a[j]; s2 += a[j] * a[j]; }
#pragma unroll
  for (int off = 1; off < 64; off <<= 1) { s1 += __shfl_xor(s1, off); s2 += __shfl_xor(s2, off); }
  float mean = s1 * (1.f / 512.f);
  float rstd = rsqrtf(s2 * (1.f / 512.f) - mean * mean + 1e-5f);
  unsigned short o[8] __attribute__((aligned(16)));
#pragma unroll
  for (int j = 0; j < 8; ++j) {
    float v = (a[j] - mean) * rstd * gam[n0 + j] + bet[n0 + j];
    v = v > 0.f ? v : 0.01f * v;
    o[j] = f2bf(v);
  }
  *(uint4*)(Y + row * 512 + n0) = *(const uint4*)o;
}

// ---------------------------------------------------------------------------
// ODE megakernel. A (64x512) resident in tiled LDS [mt][kk][qd][ml][8];
// B fragments stream global->VGPR (per-wave-private), no K-loop barriers.
// ---------------------------------------------------------------------------

// element (row, n) address in tiled A (ushort index)
static __device__ __forceinline__ int a_addr(int row, int n) {
  return (((row >> 4) * 16 + (n >> 5)) * 4 + ((n >> 3) & 3)) * 128 + (row & 15) * 8 + (n & 7);
}

static __device__ __forceinline__ void bload(const unsigned short* __restrict__ Wt, int kk,
                                             int wv, int lane, bf16x8 (&b)[4]) {
#pragma unroll
  for (int ni = 0; ni < 4; ++ni)
    b[ni] = *(const bf16x8*)(Wt + ((size_t)kk * 32 + 4 * wv + ni) * 512 + (size_t)lane * 8);
}

// bb must hold Wt slabs {0,1} on entry; holds Wnext slabs {0,1} on exit.
static __device__ __forceinline__ void gemm64d(const unsigned short* __restrict__ Wt,
                                               const unsigned short* __restrict__ Wnext,
                                               const unsigned short* As, int wv, int lane,
                                               bf16x8 (&bb)[2][4], floatx4 (&acc)[4][4]) {
#pragma unroll
  for (int mt = 0; mt < 4; ++mt)
#pragma unroll
    for (int ni = 0; ni < 4; ++ni) acc[mt][ni] = 0.f;
#pragma unroll
  for (int kk = 0; kk < 16; ++kk) {
    bf16x8 a[4];
#pragma unroll
    for (int mt = 0; mt < 4; ++mt) a[mt] = *(const bf16x8*)&As[(mt * 16 + kk) * 512 + lane * 8];
#pragma unroll
    for (int mt = 0; mt < 4; ++mt)
#pragma unroll
      for (int ni = 0; ni < 4; ++ni)
        acc[mt][ni] =
            __builtin_amdgcn_mfma_f32_16x16x32_bf16(a[mt], bb[kk & 1][ni], acc[mt][ni], 0, 0, 0);
    // refill the just-consumed slot: kk+2 of this weight, or next weight's 0/1
    if (kk < 14) bload(Wt, kk + 2, wv, lane, bb[kk & 1]);
    else bload(Wnext, kk - 14, wv, lane, bb[kk & 1]);
  }
}

// LN + leaky epilogue; writes bf16 result into tiled As.
static __device__ __forceinline__ void ln_epi64(floatx4 (&acc)[4][4], unsigned short* As,
                                                const unsigned short* Ps, int pb, int pg, int pbe,
                                                bool addt, float tval, int wv, int lane, int tid,
                                                float2* red, float* stat) {
  const int ml = lane & 15, qd = lane >> 4;
#pragma unroll
  for (int ni = 0; ni < 4; ++ni) {
    int n = (4 * wv + ni) * 16 + ml;
    float bias = bf2f(Ps[pb * 512 + n]);
    if (addt) bias += tval * bf2f(Ps[512 + n]);
#pragma unroll
    for (int mt = 0; mt < 4; ++mt)
#pragma unroll
      for (int r = 0; r < 4; ++r) acc[mt][ni][r] += bias;
  }
#pragma unroll
  for (int mt = 0; mt < 4; ++mt)
#pragma unroll
    for (int r = 0; r < 4; ++r) {
      float s1 = 0.f, s2 = 0.f;
#pragma unroll
      for (int ni = 0; ni < 4; ++ni) { float x = acc[mt][ni][r]; s1 += x; s2 += x * x; }
#pragma unroll
      for (int off = 1; off < 16; off <<= 1) { s1 += __shfl_xor(s1, off); s2 += __shfl_xor(s2, off); }
      if (ml == 0) red[(mt * 16 + 4 * qd + r) * 8 + wv] = make_float2(s1, s2);
    }
  barrier_lds();  // red visible; also: all waves past their As a-frag reads
  if (tid < 64) {
    float S1 = 0.f, S2 = 0.f;
#pragma unroll
    for (int w = 0; w < 8; ++w) { float2 v = red[tid * 8 + w]; S1 += v.x; S2 += v.y; }
    float mean = S1 * (1.f / 512.f);
    float var = S2 * (1.f / 512.f) - mean * mean;
    stat[tid * 2] = mean;
    stat[tid * 2 + 1] = rsqrtf(var + 1e-5f);
  }
  barrier_lds();
#pragma unroll
  for (int mt = 0; mt < 4; ++mt)
#pragma unroll
    for (int r = 0; r < 4; ++r) {
      int row = mt * 16 + 4 * qd + r;
      float mean = stat[row * 2], rstd = stat[row * 2 + 1];
#pragma unroll
      for (int ni = 0; ni < 4; ++ni) {
        int n = (4 * wv + ni) * 16 + ml;
        float x = (acc[mt][ni][r] - mean) * rstd * bf2f(Ps[pg * 512 + n]) + bf2f(Ps[pbe * 512 + n]);
        x = x > 0.f ? x : 0.01f * x;
        As[a_addr(row, n)] = f2bf(x);
      }
    }
  barrier_lds();  // As writes visible
}

// RK4 stage: k = acc + bout; h fp32, ksum packed bf16 pairs; writes y into As.
static __device__ __forceinline__ void stage_epi64(floatx4 (&acc)[4][4], float (&h)[4][4][4],
                                                   unsigned int (&ks)[4][4][2], unsigned short* As,
                                                   const unsigned short* Ps, int stg, int wv,
                                                   int lane) {
  const int ml = lane & 15, qd = lane >> 4;
  barrier_lds();  // K-loop has no barriers: ensure all waves done reading As
#pragma unroll
  for (int mt = 0; mt < 4; ++mt)
#pragma unroll
    for (int ni = 0; ni < 4; ++ni) {
      int n = (4 * wv + ni) * 16 + ml;
      float bias = bf2f(Ps[7 * 512 + n]);
#pragma unroll
      for (int rp = 0; rp < 2; ++rp) {
        float kv0 = acc[mt][ni][2 * rp] + bias;
        float kv1 = acc[mt][ni][2 * rp + 1] + bias;
        unsigned int pk = ks[mt][ni][rp];
        float s0 = bf2f((unsigned short)(pk & 0xffffu));
        float s1 = bf2f((unsigned short)(pk >> 16));
        float h0 = h[mt][ni][2 * rp], h1 = h[mt][ni][2 * rp + 1];
        float y0, y1;
        if (stg == 0)      { s0 = kv0;        s1 = kv1;        y0 = h0 + 0.125f * kv0; y1 = h1 + 0.125f * kv1; }
        else if (stg == 1) { s0 += 2.f * kv0; s1 += 2.f * kv1; y0 = h0 + 0.125f * kv0; y1 = h1 + 0.125f * kv1; }
        else if (stg == 2) { s0 += 2.f * kv0; s1 += 2.f * kv1; y0 = h0 + 0.25f * kv0;  y1 = h1 + 0.25f * kv1; }
        else {
          h0 += (1.f / 24.f) * (s0 + kv0);  // dt/6, dt=0.25
          h1 += (1.f / 24.f) * (s1 + kv1);
          h[mt][ni][2 * rp] = h0; h[mt][ni][2 * rp + 1] = h1;
          y0 = h0; y1 = h1;
        }
        ks[mt][ni][rp] = (unsigned int)f2bf(s0) | ((unsigned int)f2bf(s1) << 16);
        int row = mt * 16 + 4 * qd + 2 * rp;
        As[a_addr(row, n)] = f2bf(y0);
        As[a_addr(row + 1, n)] = f2bf(y1);
      }
    }
  barrier_lds();  // As writes visible
}

__global__ __launch_bounds__(512) __attribute__((amdgpu_waves_per_eu(2))) void ode_mega(
    const unsigned short* Y, const unsigned short* __restrict__ W1t,
    const unsigned short* __restrict__ W2t, const unsigned short* __restrict__ Wot,
    const float* __restrict__ b1, const float* __restrict__ tr, const float* __restrict__ g1,
    const float* __restrict__ be1, const float* __restrict__ b2, const float* __restrict__ g2,
    const float* __restrict__ be2, const float* __restrict__ bo, unsigned short* Yout) {
  __shared__ __align__(16) unsigned short As[32768];  // 64KB tiled A
  __shared__ __align__(16) unsigned short Ps[4096];   // 8KB params
  __shared__ float2 red[1024];                        // 8KB (oversized on purpose:
  __shared__ float stat[128];                         //  total 82432B > 80KB -> 1 block/CU
                                                      //  -> allocator targets 2 waves/EU
                                                      //  -> 256-VGPR budget, no spills)
  const int tid = threadIdx.x;
  const int lane = tid & 63;
  const int wv = tid >> 6;
  const int ml = lane & 15;
  const int qd = lane >> 4;
  const size_t m0 = (size_t)blockIdx.x * 64;

  // start weight prefetch immediately
  bf16x8 bb[2][4];
  bload(W1t, 0, wv, lane, bb[0]);
  bload(W1t, 1, wv, lane, bb[1]);

  {
    const float* srcs[8] = {b1, tr, g1, be1, b2, g2, be2, bo};
#pragma unroll
    for (int v = 0; v < 8; ++v) Ps[v * 512 + tid] = f2bf(srcs[v][tid]);
  }
  // stage initial A: thread owns row r = tid>>3, chunks c = i*8 + (tid&7)
  {
    int r = tid >> 3;
#pragma unroll
    for (int i = 0; i < 8; ++i) {
      int c = i * 8 + (tid & 7);
      uint4 v = *(const uint4*)(Y + (m0 + r) * 512 + c * 8);
      int dst = (((r >> 4) * 16 + (c >> 2)) * 4 + (c & 3)) * 128 + (r & 15) * 8;
      *(uint4*)(As + dst) = v;
    }
  }
  barrier_lds();

  float h[4][4][4];          // fp32 ODE state, MFMA C-layout
  unsigned int ks[4][4][2];  // RK4 ksum, packed bf16 pairs
#pragma unroll
  for (int mt = 0; mt < 4; ++mt)
#pragma unroll
    for (int ni = 0; ni < 4; ++ni) {
      ks[mt][ni][0] = 0u; ks[mt][ni][1] = 0u;
      int n = (4 * wv + ni) * 16 + ml;
#pragma unroll
      for (int r = 0; r < 4; ++r) h[mt][ni][r] = bf2f(As[a_addr(mt * 16 + 4 * qd + r, n)]);
    }

  for (int e = 0; e < 16; ++e) {  // 4 RK4 steps x 4 stages
    int stg = e & 3;
    float tval = 0.25f * (float)(e >> 2) + ((stg == 3) ? 0.25f : (stg ? 0.125f : 0.f));
    floatx4 acc[4][4];
    gemm64d(W1t, W2t, As, wv, lane, bb, acc);
    ln_epi64(acc, As, Ps, 0, 2, 3, true, tval, wv, lane, tid, red, stat);
    gemm64d(W2t, Wot, As, wv, lane, bb, acc);
    ln_epi64(acc, As, Ps, 4, 5, 6, false, 0.f, wv, lane, tid, red, stat);
    gemm64d(Wot, W1t, As, wv, lane, bb, acc);  // preloads next eval's W1
    stage_epi64(acc, h, ks, As, Ps, stg, wv, lane);
  }

  // final h_ode (bf16, row-major) for the GRU phase
#pragma unroll
  for (int mt = 0; mt < 4; ++mt)
#pragma unroll
    for (int ni = 0; ni < 4; ++ni)
#pragma unroll
      for (int r = 0; r < 4; ++r) {
        size_t row = m0 + mt * 16 + 4 * qd + r;
        int n = (4 * wv + ni) * 16 + ml;
        Yout[row * 512 + n] = f2bf(h[mt][ni][r]);
      }
}

// ---------------------------------------------------------------------------
// GRU step (unchanged): gi = y_t @ W_ih, gh = h_prev @ W_hh, gates.
// grid (32, 8): 32 rows x 64 gate-cols per block, 4 waves.
// ---------------------------------------------------------------------------
__global__ __launch_bounds__(256) void gru_step(
    const unsigned short* __restrict__ Yt, const float* __restrict__ hprev,
    float* __restrict__ hnew, const unsigned short* __restrict__ Wiht,
    const unsigned short* __restrict__ Whht, const float* __restrict__ bih,
    const float* __restrict__ bhh) {
  __shared__ __align__(16) unsigned short Ay[32 * BP];
  __shared__ __align__(16) unsigned short Ah[32 * BP];
  __shared__ __align__(16) unsigned short Bg[6 * 64 * BP];
  const int tid = threadIdx.x, lane = tid & 63, wv = tid >> 6;
  const int ml = lane & 15, qd = lane >> 4;
  const int m0 = blockIdx.x * 32;
  const int j0 = blockIdx.y * 64;

  floatx4 acc[2][6];
#pragma unroll
  for (int mi = 0; mi < 2; ++mi)
#pragma unroll
    for (int g = 0; g < 6; ++g) acc[mi][g] = 0.f;

  for (int kk = 0; kk < 16; ++kk) {
    __syncthreads();
#pragma unroll
    for (int c = 0; c < 7; ++c) {
      int id = c * 256 + tid;
      if (id < 128) {
        int r = id >> 2, kc = id & 3;
        *(uint4*)(Ay + r * BP + kc * 8) =
            *(const uint4*)(Yt + (size_t)(m0 + r) * 512 + kk * 32 + kc * 8);
      } else if (id < 256) {
        int id2 = id - 128;
        int r = id2 >> 2, kc = id2 & 3;
        const float* s = hprev + (size_t)(m0 + r) * 512 + kk * 32 + kc * 8;
        unsigned short o[8] __attribute__((aligned(16)));
#pragma unroll
        for (int j = 0; j < 8; ++j) o[j] = f2bf(s[j]);
        *(uint4*)(Ah + r * BP + kc * 8) = *(const uint4*)o;
      } else {
        int id2 = id - 256;
        int g = id2 >> 8;
        int rem = id2 & 255;
        int r = rem >> 2, kc = rem & 3;
        const unsigned short* mat = (g < 3) ? Wiht : Whht;
        int gate = (g < 3) ? g : (g - 3);
        *(uint4*)(Bg + g * (64 * BP) + r * BP + kc * 8) =
            *(const uint4*)(mat + (size_t)(gate * 512 + j0 + r) * 512 + kk * 32 + kc * 8);
      }
    }
    __syncthreads();
    bf16x8 ay[2], ah[2];
#pragma unroll
    for (int mi = 0; mi < 2; ++mi) {
      ay[mi] = *(const bf16x8*)&Ay[(16 * mi + ml) * BP + qd * 8];
      ah[mi] = *(const bf16x8*)&Ah[(16 * mi + ml) * BP + qd * 8];
    }
#pragma unroll
    for (int g = 0; g < 6; ++g) {
      bf16x8 b = *(const bf16x8*)&Bg[g * (64 * BP) + (16 * wv + ml) * BP + qd * 8];
#pragma unroll
      for (int mi = 0; mi < 2; ++mi)
        acc[mi][g] = __builtin_amdgcn_mfma_f32_16x16x32_bf16((g < 3) ? ay[mi] : ah[mi], b,
                                                             acc[mi][g], 0, 0, 0);
    }
  }
  int j = j0 + 16 * wv + ml;
  float bi_r = bih[j], bi_z = bih[512 + j], bi_n = bih[1024 + j];
  float bh_r = bhh[j], bh_z = bhh[512 + j], bh_n = bhh[1024 + j];
#pragma unroll
  for (int mi = 0; mi < 2; ++mi)
#pragma unroll
    for (int r = 0; r < 4; ++r) {
      size_t row = (size_t)(m0 + 16 * mi + 4 * qd + r);
      float rg = acc[mi][0][r] + bi_r + acc[mi][3][r] + bh_r;
      rg = 1.f / (1.f + __expf(-rg));
      float zg = acc[mi][1][r] + bi_z + acc[mi][4][r] + bh_z;
      zg = 1.f / (1.f + __expf(-zg));
      float ng = tanhf(acc[mi][2][r] + bi_n + rg * (acc[mi][5][r] + bh_n));
      float hp = hprev[row * 512 + j];
      hnew[row * 512 + j] = (1.f - zg) * ng + zg * hp;
    }
}

__global__ void zero_h(float* hf) {
  int i = blockIdx.x * 256 + threadIdx.x;
  hf[i] = 0.f;
}

// ---------------------------------------------------------------------------
extern "C" void kernel_launch(void* const* d_in, const int* in_sizes, int n_in,
                              void* d_out, int out_size, void* d_ws, size_t ws_size,
                              hipStream_t stream) {
  (void)in_sizes; (void)n_in; (void)out_size; (void)ws_size;
  const float* xs    = (const float*)d_in[0];
  const float* obsW  = (const float*)d_in[1];
  const float* obsb  = (const float*)d_in[2];
  const float* obsg  = (const float*)d_in[3];
  const float* obsbe = (const float*)d_in[4];
  const float* W1    = (const float*)d_in[5];
  const float* b1    = (const float*)d_in[6];
  const float* g1    = (const float*)d_in[7];
  const float* be1   = (const float*)d_in[8];
  const float* W2    = (const float*)d_in[9];
  const float* b2    = (const float*)d_in[10];
  const float* g2    = (const float*)d_in[11];
  const float* be2   = (const float*)d_in[12];
  const float* Wo    = (const float*)d_in[13];
  const float* bo    = (const float*)d_in[14];
  const float* Wih   = (const float*)d_in[15];
  const float* bih   = (const float*)d_in[16];
  const float* Whh   = (const float*)d_in[17];
  const float* bhh   = (const float*)d_in[18];

  char* p = (char*)d_ws;
  auto take = [&](size_t bytes) { char* q = p; p += (bytes + 255) & ~(size_t)255; return q; };
  unsigned short* W1t  = (unsigned short*)take((size_t)512 * 512 * 2);
  unsigned short* W2t  = (unsigned short*)take((size_t)512 * 512 * 2);
  unsigned short* Wot  = (unsigned short*)take((size_t)512 * 512 * 2);
  unsigned short* Wiht = (unsigned short*)take((size_t)1536 * 512 * 2);
  unsigned short* Whht = (unsigned short*)take((size_t)1536 * 512 * 2);
  float* hf0 = (float*)take((size_t)1024 * 512 * 4);
  float* hf1 = (float*)take((size_t)1024 * 512 * 4);
  unsigned short* Yb = (unsigned short*)take((size_t)65536 * 512 * 2);

  dim3 tb(32, 8);
  tile_weight<<<128, 256, 0, stream>>>(W1, W1t);  // first 512 of 513 rows
  tile_weight<<<128, 256, 0, stream>>>(W2, W2t);
  tile_weight<<<128, 256, 0, stream>>>(Wo, Wot);
  transpose_f2b<<<dim3(48, 16), tb, 0, stream>>>(Wih, Wiht, 512, 1536);
  transpose_f2b<<<dim3(48, 16), tb, 0, stream>>>(Whh, Whht, 512, 1536);

  obs_embed<<<16384, 256, 0, stream>>>(xs, obsW, obsb, obsg, obsbe, Yb);

  // tr = W1 row 512 (time row), folded into layer-1 bias per eval.
  ode_mega<<<1024, 512, 0, stream>>>(Yb, W1t, W2t, Wot, b1, W1 + 512 * 512, g1, be1, b2, g2,
                                     be2, bo, Yb);

  zero_h<<<2048, 256, 0, stream>>>(hf0);
  float* hf[2] = {hf0, hf1};
  for (int t = 0; t < 64; ++t) {
    int s = t & 1, d = s ^ 1;
    float* hn = (t == 63) ? (float*)d_out : hf[d];
    gru_step<<<dim3(32, 8), 256, 0, stream>>>(Yb + (size_t)t * 1024 * 512, hf[s], hn, Wiht, Whht,
                                              bih, bhh);
  }
}

// Round 8
// 5915.911 us; speedup vs baseline: 2.3408x; 1.2729x over previous
//
#include <hip/hip_runtime.h>
#include <stdint.h>

// ---------------------------------------------------------------------------
// ODE-RNN encoder, f32 I/O, bf16 MFMA internals.
// R8 = R6's 16-wave split (per-wave live state ~110 regs: acc32+h32+ks16+bb32)
//    + R7's LDS inflation (82.4KB -> 1 block/CU -> 16 waves = 4/EU, so the
//      compiler's 128-reg ceiling IS the hardware budget)
//    + K-loop `unroll 2` instead of full unroll (R5-R7's full unroll blew
//      live ranges -> 3GB scratch churn at any wave count).
// B operand: global->VGPR per-wave (coalesced via tiled weights), K-loop
// barrier-free, epilogue barriers lgkm-only so prefetches stay in flight.
// ---------------------------------------------------------------------------

typedef __bf16 bf16x8 __attribute__((ext_vector_type(8)));
typedef float floatx4 __attribute__((ext_vector_type(4)));

#define BP 40  // gru_step padded B row (ushorts)

static __device__ __forceinline__ float bf2f(unsigned short u) {
  union { unsigned int u32; float f; } c;
  c.u32 = ((unsigned int)u) << 16;
  return c.f;
}
static __device__ __forceinline__ unsigned short f2bf(float f) {
  union { __bf16 h; unsigned short u; } c;
  c.h = (__bf16)f;  // RNE
  return c.u;
}

// LDS-only barrier: does NOT drain vmcnt, so global prefetches stay in flight.
static __device__ __forceinline__ void barrier_lds() {
  __asm__ volatile("s_waitcnt lgkmcnt(0)\n\ts_barrier" ::: "memory");
}

// ---------------------------------------------------------------------------
// tile_weight: W (K=512 x N=512, f32 row-major) -> bf16 tiled
// [kk(16)][nt(32)][qd(4)][ml(16)][8]; element (kk,nt,qd,ml,j) = W[kk*32+qd*8+j][nt*16+ml]
// ---------------------------------------------------------------------------
__global__ void tile_weight(const float* __restrict__ src, unsigned short* __restrict__ dst) {
  int t = blockIdx.x * 256 + threadIdx.x;  // 0..32767
  int ml = t & 15, qd = (t >> 4) & 3;
  int nt = (t >> 6) & 31, kk = t >> 11;
  int n = nt * 16 + ml;
  int k0 = kk * 32 + qd * 8;
  unsigned short o[8] __attribute__((aligned(16)));
#pragma unroll
  for (int j = 0; j < 8; ++j) o[j] = f2bf(src[(size_t)(k0 + j) * 512 + n]);
  *(uint4*)(dst + (size_t)t * 8) = *(const uint4*)o;
}

// ---------------------------------------------------------------------------
// transpose + f32->bf16 (GRU weights, [n][k] flat layout)
// ---------------------------------------------------------------------------
__global__ void transpose_f2b(const float* __restrict__ src, unsigned short* __restrict__ dst,
                              int R, int C) {
  __shared__ float t[32][33];
  int c0 = blockIdx.x * 32, r0 = blockIdx.y * 32;
  int tx = threadIdx.x, ty = threadIdx.y;  // 32 x 8
#pragma unroll
  for (int i = 0; i < 32; i += 8) t[ty + i][tx] = src[(size_t)(r0 + ty + i) * C + c0 + tx];
  __syncthreads();
#pragma unroll
  for (int i = 0; i < 32; i += 8) dst[(size_t)(c0 + ty + i) * R + r0 + tx] = f2bf(t[tx][ty + i]);
}

// ---------------------------------------------------------------------------
// obs embed: y = leaky(LN(xs @ W + b)) (f32 in, bf16 out), one wave per row
// ---------------------------------------------------------------------------
__global__ __launch_bounds__(256) void obs_embed(
    const float* __restrict__ xs, const float* __restrict__ W,
    const float* __restrict__ bias, const float* __restrict__ gam,
    const float* __restrict__ bet, unsigned short* __restrict__ Y) {
  __shared__ float Wl[4096];
  const int tid = threadIdx.x, lane = tid & 63, wv = tid >> 6;
#pragma unroll
  for (int i = 0; i < 16; ++i) Wl[i * 256 + tid] = W[i * 256 + tid];
  __syncthreads();
  size_t row = (size_t)blockIdx.x * 4 + wv;
  float xf[8];
  {
    const float* xp = xs + row * 8;
#pragma unroll
    for (int k = 0; k < 8; ++k) xf[k] = xp[k];
  }
  int n0 = lane * 8;
  float a[8];
#pragma unroll
  for (int j = 0; j < 8; ++j) a[j] = bias[n0 + j];
#pragma unroll
  for (int k = 0; k < 8; ++k)
#pragma unroll
    for (int j = 0; j < 8; ++j) a[j] += xf[k] * Wl[k * 512 + n0 + j];
  float s1 = 0.f, s2 = 0.f;
#pragma unroll
  for (int j = 0; j < 8; ++j) { s1 += a[j]; s2 += a[j] * a[j]; }
#pragma unroll
  for (int off = 1; off < 64; off <<= 1) { s1 += __shfl_xor(s1, off); s2 += __shfl_xor(s2, off); }
  float mean = s1 * (1.f / 512.f);
  float rstd = rsqrtf(s2 * (1.f / 512.f) - mean * mean + 1e-5f);
  unsigned short o[8] __attribute__((aligned(16)));
#pragma unroll
  for (int j = 0; j < 8; ++j) {
    float v = (a[j] - mean) * rstd * gam[n0 + j] + bet[n0 + j];
    v = v > 0.f ? v : 0.01f * v;
    o[j] = f2bf(v);
  }
  *(uint4*)(Y + row * 512 + n0) = *(const uint4*)o;
}

// ---------------------------------------------------------------------------
// ODE megakernel. A (64x512) resident in tiled LDS [mt][kk][qd][ml][8];
// 16 waves: wm = wv>>3 owns M-tiles {2wm,2wm+1}, wy = wv&7 owns N-tiles
// {4wy..4wy+3}. B fragments stream global->VGPR; K-loop barrier-free.
// ---------------------------------------------------------------------------

// element (row, n) address in tiled A (ushort index)
static __device__ __forceinline__ int a_addr(int row, int n) {
  return (((row >> 4) * 16 + (n >> 5)) * 4 + ((n >> 3) & 3)) * 128 + (row & 15) * 8 + (n & 7);
}

static __device__ __forceinline__ void bload(const unsigned short* __restrict__ Wt, int kk,
                                             int wy, int lane, bf16x8 (&b)[4]) {
#pragma unroll
  for (int ni = 0; ni < 4; ++ni)
    b[ni] = *(const bf16x8*)(Wt + ((size_t)kk * 32 + 4 * wy + ni) * 512 + (size_t)lane * 8);
}

// bb must hold Wt slabs {0,1} on entry; holds Wnext slabs {0,1} on exit.
static __device__ __forceinline__ void gemm64d(const unsigned short* __restrict__ Wt,
                                               const unsigned short* __restrict__ Wnext,
                                               const unsigned short* As, int wm, int wy, int lane,
                                               bf16x8 (&bb)[2][4], floatx4 (&acc)[2][4]) {
#pragma unroll
  for (int mi = 0; mi < 2; ++mi)
#pragma unroll
    for (int ni = 0; ni < 4; ++ni) acc[mi][ni] = 0.f;
#pragma unroll 2
  for (int kk = 0; kk < 16; ++kk) {  // unroll 2 (dbuf parity), NOT full: keeps
    bf16x8 a[2];                     // load live-ranges short -> no spill churn
#pragma unroll
    for (int mi = 0; mi < 2; ++mi)
      a[mi] = *(const bf16x8*)&As[((wm * 2 + mi) * 16 + kk) * 512 + lane * 8];
#pragma unroll
    for (int mi = 0; mi < 2; ++mi)
#pragma unroll
      for (int ni = 0; ni < 4; ++ni)
        acc[mi][ni] =
            __builtin_amdgcn_mfma_f32_16x16x32_bf16(a[mi], bb[kk & 1][ni], acc[mi][ni], 0, 0, 0);
    // refill the just-consumed slot: kk+2 of this weight, or next weight's 0/1
    if (kk < 14) bload(Wt, kk + 2, wy, lane, bb[kk & 1]);
    else bload(Wnext, kk - 14, wy, lane, bb[kk & 1]);
  }
}

// LN + leaky epilogue; writes bf16 result into tiled As.
static __device__ __forceinline__ void ln_epi64(floatx4 (&acc)[2][4], unsigned short* As,
                                                const unsigned short* Ps, int pb, int pg, int pbe,
                                                bool addt, float tval, int wm, int wy, int lane,
                                                int tid, float2* red, float* stat) {
  const int ml = lane & 15, qd = lane >> 4;
#pragma unroll
  for (int ni = 0; ni < 4; ++ni) {
    int n = (4 * wy + ni) * 16 + ml;
    float bias = bf2f(Ps[pb * 512 + n]);
    if (addt) bias += tval * bf2f(Ps[512 + n]);
#pragma unroll
    for (int mi = 0; mi < 2; ++mi)
#pragma unroll
      for (int r = 0; r < 4; ++r) acc[mi][ni][r] += bias;
  }
#pragma unroll
  for (int mi = 0; mi < 2; ++mi)
#pragma unroll
    for (int r = 0; r < 4; ++r) {
      float s1 = 0.f, s2 = 0.f;
#pragma unroll
      for (int ni = 0; ni < 4; ++ni) { float x = acc[mi][ni][r]; s1 += x; s2 += x * x; }
#pragma unroll
      for (int off = 1; off < 16; off <<= 1) { s1 += __shfl_xor(s1, off); s2 += __shfl_xor(s2, off); }
      if (ml == 0) red[((wm * 2 + mi) * 16 + 4 * qd + r) * 8 + wy] = make_float2(s1, s2);
    }
  barrier_lds();  // red visible; all waves past their As a-frag reads
  if (tid < 64) {
    float S1 = 0.f, S2 = 0.f;
#pragma unroll
    for (int w = 0; w < 8; ++w) { float2 v = red[tid * 8 + w]; S1 += v.x; S2 += v.y; }
    float mean = S1 * (1.f / 512.f);
    float var = S2 * (1.f / 512.f) - mean * mean;
    stat[tid * 2] = mean;
    stat[tid * 2 + 1] = rsqrtf(var + 1e-5f);
  }
  barrier_lds();
#pragma unroll
  for (int mi = 0; mi < 2; ++mi)
#pragma unroll
    for (int r = 0; r < 4; ++r) {
      int row = (wm * 2 + mi) * 16 + 4 * qd + r;
      float mean = stat[row * 2], rstd = stat[row * 2 + 1];
#pragma unroll
      for (int ni = 0; ni < 4; ++ni) {
        int n = (4 * wy + ni) * 16 + ml;
        float x = (acc[mi][ni][r] - mean) * rstd * bf2f(Ps[pg * 512 + n]) + bf2f(Ps[pbe * 512 + n]);
        x = x > 0.f ? x : 0.01f * x;
        As[a_addr(row, n)] = f2bf(x);
      }
    }
  barrier_lds();  // As writes visible
}

// RK4 stage: k = acc + bout; h fp32, ksum packed bf16 pairs; writes y into As.
static __device__ __forceinline__ void stage_epi64(floatx4 (&acc)[2][4], float (&h)[2][4][4],
                                                   unsigned int (&ks)[2][4][2], unsigned short* As,
                                                   const unsigned short* Ps, int stg, int wm,
                                                   int wy, int lane) {
  const int ml = lane & 15, qd = lane >> 4;
  barrier_lds();  // K-loop has no barriers: ensure all waves done reading As
#pragma unroll
  for (int mi = 0; mi < 2; ++mi)
#pragma unroll
    for (int ni = 0; ni < 4; ++ni) {
      int n = (4 * wy + ni) * 16 + ml;
      float bias = bf2f(Ps[7 * 512 + n]);
#pragma unroll
      for (int rp = 0; rp < 2; ++rp) {
        float kv0 = acc[mi][ni][2 * rp] + bias;
        float kv1 = acc[mi][ni][2 * rp + 1] + bias;
        unsigned int pk = ks[mi][ni][rp];
        float s0 = bf2f((unsigned short)(pk & 0xffffu));
        float s1 = bf2f((unsigned short)(pk >> 16));
        float h0 = h[mi][ni][2 * rp], h1 = h[mi][ni][2 * rp + 1];
        float y0, y1;
        if (stg == 0)      { s0 = kv0;        s1 = kv1;        y0 = h0 + 0.125f * kv0; y1 = h1 + 0.125f * kv1; }
        else if (stg == 1) { s0 += 2.f * kv0; s1 += 2.f * kv1; y0 = h0 + 0.125f * kv0; y1 = h1 + 0.125f * kv1; }
        else if (stg == 2) { s0 += 2.f * kv0; s1 += 2.f * kv1; y0 = h0 + 0.25f * kv0;  y1 = h1 + 0.25f * kv1; }
        else {
          h0 += (1.f / 24.f) * (s0 + kv0);  // dt/6, dt=0.25
          h1 += (1.f / 24.f) * (s1 + kv1);
          h[mi][ni][2 * rp] = h0; h[mi][ni][2 * rp + 1] = h1;
          y0 = h0; y1 = h1;
        }
        ks[mi][ni][rp] = (unsigned int)f2bf(s0) | ((unsigned int)f2bf(s1) << 16);
        int row = (wm * 2 + mi) * 16 + 4 * qd + 2 * rp;
        As[a_addr(row, n)] = f2bf(y0);
        As[a_addr(row + 1, n)] = f2bf(y1);
      }
    }
  barrier_lds();  // As writes visible
}

__global__ __launch_bounds__(1024) __attribute__((amdgpu_waves_per_eu(4, 4))) void ode_mega(
    const unsigned short* Y, const unsigned short* __restrict__ W1t,
    const unsigned short* __restrict__ W2t, const unsigned short* __restrict__ Wot,
    const float* __restrict__ b1, const float* __restrict__ tr, const float* __restrict__ g1,
    const float* __restrict__ be1, const float* __restrict__ b2, const float* __restrict__ g2,
    const float* __restrict__ be2, const float* __restrict__ bo, unsigned short* Yout) {
  __shared__ __align__(16) unsigned short As[32768];  // 64KB tiled A
  __shared__ __align__(16) unsigned short Ps[4096];   // 8KB params
  __shared__ float2 red[1024];                        // 8KB (oversized on purpose:
  __shared__ float stat[128];                         //  total 82432B > 80KB -> 1 block/CU
                                                      //  -> 16 waves = 4/EU = 128-reg HW budget)
  const int tid = threadIdx.x;
  const int lane = tid & 63;
  const int wv = tid >> 6;   // 0..15
  const int wm = wv >> 3;    // 0..1  (M half)
  const int wy = wv & 7;     // 0..7  (N eighth)
  const int ml = lane & 15;
  const int qd = lane >> 4;
  const size_t m0 = (size_t)blockIdx.x * 64;

  // start weight prefetch immediately
  bf16x8 bb[2][4];
  bload(W1t, 0, wy, lane, bb[0]);
  bload(W1t, 1, wy, lane, bb[1]);

  if (tid < 512) {
    const float* srcs[8] = {b1, tr, g1, be1, b2, g2, be2, bo};
#pragma unroll
    for (int v = 0; v < 8; ++v) Ps[v * 512 + tid] = f2bf(srcs[v][tid]);
  }
  // stage initial A: 4096 chunks of 8 bf16 over 1024 threads
#pragma unroll
  for (int c = 0; c < 4; ++c) {
    int id = c * 1024 + tid;
    int r = id >> 6, kc = id & 63;
    uint4 v = *(const uint4*)(Y + (m0 + r) * 512 + kc * 8);
    int dst = (((r >> 4) * 16 + (kc >> 2)) * 4 + (kc & 3)) * 128 + (r & 15) * 8;
    *(uint4*)(As + dst) = v;
  }
  barrier_lds();

  float h[2][4][4];          // fp32 ODE state, MFMA C-layout
  unsigned int ks[2][4][2];  // RK4 ksum, packed bf16 pairs
#pragma unroll
  for (int mi = 0; mi < 2; ++mi)
#pragma unroll
    for (int ni = 0; ni < 4; ++ni) {
      ks[mi][ni][0] = 0u; ks[mi][ni][1] = 0u;
      int n = (4 * wy + ni) * 16 + ml;
#pragma unroll
      for (int r = 0; r < 4; ++r)
        h[mi][ni][r] = bf2f(As[a_addr((wm * 2 + mi) * 16 + 4 * qd + r, n)]);
    }

  for (int e = 0; e < 16; ++e) {  // 4 RK4 steps x 4 stages
    int stg = e & 3;
    float tval = 0.25f * (float)(e >> 2) + ((stg == 3) ? 0.25f : (stg ? 0.125f : 0.f));
    floatx4 acc[2][4];
    gemm64d(W1t, W2t, As, wm, wy, lane, bb, acc);
    ln_epi64(acc, As, Ps, 0, 2, 3, true, tval, wm, wy, lane, tid, red, stat);
    gemm64d(W2t, Wot, As, wm, wy, lane, bb, acc);
    ln_epi64(acc, As, Ps, 4, 5, 6, false, 0.f, wm, wy, lane, tid, red, stat);
    gemm64d(Wot, W1t, As, wm, wy, lane, bb, acc);  // preloads next eval's W1
    stage_epi64(acc, h, ks, As, Ps, stg, wm, wy, lane);
  }

  // final h_ode (bf16, row-major) for the GRU phase
#pragma unroll
  for (int mi = 0; mi < 2; ++mi)
#pragma unroll
    for (int ni = 0; ni < 4; ++ni)
#pragma unroll
      for (int r = 0; r < 4; ++r) {
        size_t row = m0 + (wm * 2 + mi) * 16 + 4 * qd + r;
        int n = (4 * wy + ni) * 16 + ml;
        Yout[row * 512 + n] = f2bf(h[mi][ni][r]);
      }
}

// ---------------------------------------------------------------------------
// GRU step (unchanged): gi = y_t @ W_ih, gh = h_prev @ W_hh, gates.
// grid (32, 8): 32 rows x 64 gate-cols per block, 4 waves.
// ---------------------------------------------------------------------------
__global__ __launch_bounds__(256) void gru_step(
    const unsigned short* __restrict__ Yt, const float* __restrict__ hprev,
    float* __restrict__ hnew, const unsigned short* __restrict__ Wiht,
    const unsigned short* __restrict__ Whht, const float* __restrict__ bih,
    const float* __restrict__ bhh) {
  __shared__ __align__(16) unsigned short Ay[32 * BP];
  __shared__ __align__(16) unsigned short Ah[32 * BP];
  __shared__ __align__(16) unsigned short Bg[6 * 64 * BP];
  const int tid = threadIdx.x, lane = tid & 63, wv = tid >> 6;
  const int ml = lane & 15, qd = lane >> 4;
  const int m0 = blockIdx.x * 32;
  const int j0 = blockIdx.y * 64;

  floatx4 acc[2][6];
#pragma unroll
  for (int mi = 0; mi < 2; ++mi)
#pragma unroll
    for (int g = 0; g < 6; ++g) acc[mi][g] = 0.f;

  for (int kk = 0; kk < 16; ++kk) {
    __syncthreads();
#pragma unroll
    for (int c = 0; c < 7; ++c) {
      int id = c * 256 + tid;
      if (id < 128) {
        int r = id >> 2, kc = id & 3;
        *(uint4*)(Ay + r * BP + kc * 8) =
            *(const uint4*)(Yt + (size_t)(m0 + r) * 512 + kk * 32 + kc * 8);
      } else if (id < 256) {
        int id2 = id - 128;
        int r = id2 >> 2, kc = id2 & 3;
        const float* s = hprev + (size_t)(m0 + r) * 512 + kk * 32 + kc * 8;
        unsigned short o[8] __attribute__((aligned(16)));
#pragma unroll
        for (int j = 0; j < 8; ++j) o[j] = f2bf(s[j]);
        *(uint4*)(Ah + r * BP + kc * 8) = *(const uint4*)o;
      } else {
        int id2 = id - 256;
        int g = id2 >> 8;
        int rem = id2 & 255;
        int r = rem >> 2, kc = rem & 3;
        const unsigned short* mat = (g < 3) ? Wiht : Whht;
        int gate = (g < 3) ? g : (g - 3);
        *(uint4*)(Bg + g * (64 * BP) + r * BP + kc * 8) =
            *(const uint4*)(mat + (size_t)(gate * 512 + j0 + r) * 512 + kk * 32 + kc * 8);
      }
    }
    __syncthreads();
    bf16x8 ay[2], ah[2];
#pragma unroll
    for (int mi = 0; mi < 2; ++mi) {
      ay[mi] = *(const bf16x8*)&Ay[(16 * mi + ml) * BP + qd * 8];
      ah[mi] = *(const bf16x8*)&Ah[(16 * mi + ml) * BP + qd * 8];
    }
#pragma unroll
    for (int g = 0; g < 6; ++g) {
      bf16x8 b = *(const bf16x8*)&Bg[g * (64 * BP) + (16 * wv + ml) * BP + qd * 8];
#pragma unroll
      for (int mi = 0; mi < 2; ++mi)
        acc[mi][g] = __builtin_amdgcn_mfma_f32_16x16x32_bf16((g < 3) ? ay[mi] : ah[mi], b,
                                                             acc[mi][g], 0, 0, 0);
    }
  }
  int j = j0 + 16 * wv + ml;
  float bi_r = bih[j], bi_z = bih[512 + j], bi_n = bih[1024 + j];
  float bh_r = bhh[j], bh_z = bhh[512 + j], bh_n = bhh[1024 + j];
#pragma unroll
  for (int mi = 0; mi < 2; ++mi)
#pragma unroll
    for (int r = 0; r < 4; ++r) {
      size_t row = (size_t)(m0 + 16 * mi + 4 * qd + r);
      float rg = acc[mi][0][r] + bi_r + acc[mi][3][r] + bh_r;
      rg = 1.f / (1.f + __expf(-rg));
      float zg = acc[mi][1][r] + bi_z + acc[mi][4][r] + bh_z;
      zg = 1.f / (1.f + __expf(-zg));
      float ng = tanhf(acc[mi][2][r] + bi_n + rg * (acc[mi][5][r] + bh_n));
      float hp = hprev[row * 512 + j];
      hnew[row * 512 + j] = (1.f - zg) * ng + zg * hp;
    }
}

__global__ void zero_h(float* hf) {
  int i = blockIdx.x * 256 + threadIdx.x;
  hf[i] = 0.f;
}

// ---------------------------------------------------------------------------
extern "C" void kernel_launch(void* const* d_in, const int* in_sizes, int n_in,
                              void* d_out, int out_size, void* d_ws, size_t ws_size,
                              hipStream_t stream) {
  (void)in_sizes; (void)n_in; (void)out_size; (void)ws_size;
  const float* xs    = (const float*)d_in[0];
  const float* obsW  = (const float*)d_in[1];
  const float* obsb  = (const float*)d_in[2];
  const float* obsg  = (const float*)d_in[3];
  const float* obsbe = (const float*)d_in[4];
  const float* W1    = (const float*)d_in[5];
  const float* b1    = (const float*)d_in[6];
  const float* g1    = (const float*)d_in[7];
  const float* be1   = (const float*)d_in[8];
  const float* W2    = (const float*)d_in[9];
  const float* b2    = (const float*)d_in[10];
  const float* g2    = (const float*)d_in[11];
  const float* be2   = (const float*)d_in[12];
  const float* Wo    = (const float*)d_in[13];
  const float* bo    = (const float*)d_in[14];
  const float* Wih   = (const float*)d_in[15];
  const float* bih   = (const float*)d_in[16];
  const float* Whh   = (const float*)d_in[17];
  const float* bhh   = (const float*)d_in[18];

  char* p = (char*)d_ws;
  auto take = [&](size_t bytes) { char* q = p; p += (bytes + 255) & ~(size_t)255; return q; };
  unsigned short* W1t  = (unsigned short*)take((size_t)512 * 512 * 2);
  unsigned short* W2t  = (unsigned short*)take((size_t)512 * 512 * 2);
  unsigned short* Wot  = (unsigned short*)take((size_t)512 * 512 * 2);
  unsigned short* Wiht = (unsigned short*)take((size_t)1536 * 512 * 2);
  unsigned short* Whht = (unsigned short*)take((size_t)1536 * 512 * 2);
  float* hf0 = (float*)take((size_t)1024 * 512 * 4);
  float* hf1 = (float*)take((size_t)1024 * 512 * 4);
  unsigned short* Yb = (unsigned short*)take((size_t)65536 * 512 * 2);

  dim3 tb(32, 8);
  tile_weight<<<128, 256, 0, stream>>>(W1, W1t);  // first 512 of 513 rows
  tile_weight<<<128, 256, 0, stream>>>(W2, W2t);
  tile_weight<<<128, 256, 0, stream>>>(Wo, Wot);
  transpose_f2b<<<dim3(48, 16), tb, 0, stream>>>(Wih, Wiht, 512, 1536);
  transpose_f2b<<<dim3(48, 16), tb, 0, stream>>>(Whh, Whht, 512, 1536);

  obs_embed<<<16384, 256, 0, stream>>>(xs, obsW, obsb, obsg, obsbe, Yb);

  // tr = W1 row 512 (time row), folded into layer-1 bias per eval.
  ode_mega<<<1024, 1024, 0, stream>>>(Yb, W1t, W2t, Wot, b1, W1 + 512 * 512, g1, be1, b2, g2,
                                      be2, bo, Yb);

  zero_h<<<2048, 256, 0, stream>>>(hf0);
  float* hf[2] = {hf0, hf1};
  for (int t = 0; t < 64; ++t) {
    int s = t & 1, d = s ^ 1;
    float* hn = (t == 63) ? (float*)d_out : hf[d];
    gru_step<<<dim3(32, 8), 256, 0, stream>>>(Yb + (size_t)t * 1024 * 512, hf[s], hn, Wiht, Whht,
                                              bih, bhh);
  }
}

// Round 9
// 5905.136 us; speedup vs baseline: 2.3451x; 1.0018x over previous
//
#include <hip/hip_runtime.h>
#include <stdint.h>

// ---------------------------------------------------------------------------
// ODE-RNN encoder, f32 I/O, bf16 MFMA internals.
// R9: registers hold ONLY the GEMM working set (acc 64 + bb 32 + a 16 ~= 115
// <= the 128-reg budget the backend provisions for 512-thr blocks; R4-R8
// established budget = 2-blocks/CU heuristic, immune to attributes).
// RK4 state h (f32) and ksum (bf16) live in per-block global scratch in
// MFMA-fragment order (coalesced 256B/wave accesses, L2/L3-resident 96MB).
// Persistent grid: 512 blocks x 2 row-groups. B operand: global->VGPR dbuf,
// K-loop barrier-free, epilogue barriers lgkm-only.
// Store->load safety: every h/ks RAW pair is >=190 in-order VMEM ops apart
// (vmcnt queue depth 63 forces store retirement).
// ---------------------------------------------------------------------------

typedef __bf16 bf16x8 __attribute__((ext_vector_type(8)));
typedef float floatx4 __attribute__((ext_vector_type(4)));

#define BP 40  // gru_step padded B row (ushorts)

static __device__ __forceinline__ float bf2f(unsigned short u) {
  union { unsigned int u32; float f; } c;
  c.u32 = ((unsigned int)u) << 16;
  return c.f;
}
static __device__ __forceinline__ unsigned short f2bf(float f) {
  union { __bf16 h; unsigned short u; } c;
  c.h = (__bf16)f;  // RNE
  return c.u;
}

// LDS-only barrier: does NOT drain vmcnt, so global prefetches stay in flight.
static __device__ __forceinline__ void barrier_lds() {
  __asm__ volatile("s_waitcnt lgkmcnt(0)\n\ts_barrier" ::: "memory");
}

// ---------------------------------------------------------------------------
// tile_weight: W (K=512 x N=512, f32 row-major) -> bf16 tiled
// [kk(16)][nt(32)][qd(4)][ml(16)][8]; element (kk,nt,qd,ml,j) = W[kk*32+qd*8+j][nt*16+ml]
// ---------------------------------------------------------------------------
__global__ void tile_weight(const float* __restrict__ src, unsigned short* __restrict__ dst) {
  int t = blockIdx.x * 256 + threadIdx.x;  // 0..32767
  int ml = t & 15, qd = (t >> 4) & 3;
  int nt = (t >> 6) & 31, kk = t >> 11;
  int n = nt * 16 + ml;
  int k0 = kk * 32 + qd * 8;
  unsigned short o[8] __attribute__((aligned(16)));
#pragma unroll
  for (int j = 0; j < 8; ++j) o[j] = f2bf(src[(size_t)(k0 + j) * 512 + n]);
  *(uint4*)(dst + (size_t)t * 8) = *(const uint4*)o;
}

// ---------------------------------------------------------------------------
// transpose + f32->bf16 (GRU weights, [n][k] flat layout)
// ---------------------------------------------------------------------------
__global__ void transpose_f2b(const float* __restrict__ src, unsigned short* __restrict__ dst,
                              int R, int C) {
  __shared__ float t[32][33];
  int c0 = blockIdx.x * 32, r0 = blockIdx.y * 32;
  int tx = threadIdx.x, ty = threadIdx.y;  // 32 x 8
#pragma unroll
  for (int i = 0; i < 32; i += 8) t[ty + i][tx] = src[(size_t)(r0 + ty + i) * C + c0 + tx];
  __syncthreads();
#pragma unroll
  for (int i = 0; i < 32; i += 8) dst[(size_t)(c0 + ty + i) * R + r0 + tx] = f2bf(t[tx][ty + i]);
}

// ---------------------------------------------------------------------------
// obs embed: y = leaky(LN(xs @ W + b)) (f32 in, bf16 out), one wave per row
// ---------------------------------------------------------------------------
__global__ __launch_bounds__(256) void obs_embed(
    const float* __restrict__ xs, const float* __restrict__ W,
    const float* __restrict__ bias, const float* __restrict__ gam,
    const float* __restrict__ bet, unsigned short* __restrict__ Y) {
  __shared__ float Wl[4096];
  const int tid = threadIdx.x, lane = tid & 63, wv = tid >> 6;
#pragma unroll
  for (int i = 0; i < 16; ++i) Wl[i * 256 + tid] = W[i * 256 + tid];
  __syncthreads();
  size_t row = (size_t)blockIdx.x * 4 + wv;
  float xf[8];
  {
    const float* xp = xs + row * 8;
#pragma unroll
    for (int k = 0; k < 8; ++k) xf[k] = xp[k];
  }
  int n0 = lane * 8;
  float a[8];
#pragma unroll
  for (int j = 0; j < 8; ++j) a[j] = bias[n0 + j];
#pragma unroll
  for (int k = 0; k < 8; ++k)
#pragma unroll
    for (int j = 0; j < 8; ++j) a[j] += xf[k] * Wl[k * 512 + n0 + j];
  float s1 = 0.f, s2 = 0.f;
#pragma unroll
  for (int j = 0; j < 8; ++j) { s1 += a[j]; s2 += a[j] * a[j]; }
#pragma unroll
  for (int off = 1; off < 64; off <<= 1) { s1 += __shfl_xor(s1, off); s2 += __shfl_xor(s2, off); }
  float mean = s1 * (1.f / 512.f);
  float rstd = rsqrtf(s2 * (1.f / 512.f) - mean * mean + 1e-5f);
  unsigned short o[8] __attribute__((aligned(16)));
#pragma unroll
  for (int j = 0; j < 8; ++j) {
    float v = (a[j] - mean) * rstd * gam[n0 + j] + bet[n0 + j];
    v = v > 0.f ? v : 0.01f * v;
    o[j] = f2bf(v);
  }
  *(uint4*)(Y + row * 512 + n0) = *(const uint4*)o;
}

// ---------------------------------------------------------------------------
// ODE megakernel. A (64x512) resident in tiled LDS [mt][kk][qd][ml][8];
// 8 waves, each owning full M (4 mt) x N=64 (4 nt). B fragments stream
// global->VGPR (per-wave-private); K-loop barrier-free.
// ---------------------------------------------------------------------------

// element (row, n) address in tiled A (ushort index)
static __device__ __forceinline__ int a_addr(int row, int n) {
  return (((row >> 4) * 16 + (n >> 5)) * 4 + ((n >> 3) & 3)) * 128 + (row & 15) * 8 + (n & 7);
}
// fragment-ordered per-block state index for (wv, mt, ni, r) at lane (qd, ml)
static __device__ __forceinline__ int s_idx(int wv, int mt, int ni, int r, int qd, int ml) {
  return (((wv * 4 + mt) * 4 + ni) * 4 + r) * 64 + qd * 16 + ml;
}

static __device__ __forceinline__ void bload(const unsigned short* __restrict__ Wt, int kk,
                                             int wv, int lane, bf16x8 (&b)[4]) {
#pragma unroll
  for (int ni = 0; ni < 4; ++ni)
    b[ni] = *(const bf16x8*)(Wt + ((size_t)kk * 32 + 4 * wv + ni) * 512 + (size_t)lane * 8);
}

// bb must hold Wt slabs {0,1} on entry; holds Wnext slabs {0,1} on exit.
static __device__ __forceinline__ void gemm64d(const unsigned short* __restrict__ Wt,
                                               const unsigned short* __restrict__ Wnext,
                                               const unsigned short* As, int wv, int lane,
                                               bf16x8 (&bb)[2][4], floatx4 (&acc)[4][4]) {
#pragma unroll
  for (int mt = 0; mt < 4; ++mt)
#pragma unroll
    for (int ni = 0; ni < 4; ++ni) acc[mt][ni] = 0.f;
#pragma unroll 2
  for (int kk = 0; kk < 16; ++kk) {  // unroll 2 (dbuf parity), NOT full: keeps
    bf16x8 a[4];                     // load live-ranges short (R5-R8 lesson)
#pragma unroll
    for (int mt = 0; mt < 4; ++mt) a[mt] = *(const bf16x8*)&As[(mt * 16 + kk) * 512 + lane * 8];
#pragma unroll
    for (int mt = 0; mt < 4; ++mt)
#pragma unroll
      for (int ni = 0; ni < 4; ++ni)
        acc[mt][ni] =
            __builtin_amdgcn_mfma_f32_16x16x32_bf16(a[mt], bb[kk & 1][ni], acc[mt][ni], 0, 0, 0);
    // refill the just-consumed slot: kk+2 of this weight, or next weight's 0/1
    if (kk < 14) bload(Wt, kk + 2, wv, lane, bb[kk & 1]);
    else bload(Wnext, kk - 14, wv, lane, bb[kk & 1]);
  }
}

// LN + leaky epilogue; writes bf16 result into tiled As.
static __device__ __forceinline__ void ln_epi64(floatx4 (&acc)[4][4], unsigned short* As,
                                                const unsigned short* Ps, int pb, int pg, int pbe,
                                                bool addt, float tval, int wv, int lane, int tid,
                                                float2* red, float* stat) {
  const int ml = lane & 15, qd = lane >> 4;
#pragma unroll
  for (int ni = 0; ni < 4; ++ni) {
    int n = (4 * wv + ni) * 16 + ml;
    float bias = bf2f(Ps[pb * 512 + n]);
    if (addt) bias += tval * bf2f(Ps[512 + n]);
#pragma unroll
    for (int mt = 0; mt < 4; ++mt)
#pragma unroll
      for (int r = 0; r < 4; ++r) acc[mt][ni][r] += bias;
  }
#pragma unroll
  for (int mt = 0; mt < 4; ++mt)
#pragma unroll
    for (int r = 0; r < 4; ++r) {
      float s1 = 0.f, s2 = 0.f;
#pragma unroll
      for (int ni = 0; ni < 4; ++ni) { float x = acc[mt][ni][r]; s1 += x; s2 += x * x; }
#pragma unroll
      for (int off = 1; off < 16; off <<= 1) { s1 += __shfl_xor(s1, off); s2 += __shfl_xor(s2, off); }
      if (ml == 0) red[(mt * 16 + 4 * qd + r) * 8 + wv] = make_float2(s1, s2);
    }
  barrier_lds();  // red visible; also: all waves past their As a-frag reads
  if (tid < 64) {
    float S1 = 0.f, S2 = 0.f;
#pragma unroll
    for (int w = 0; w < 8; ++w) { float2 v = red[tid * 8 + w]; S1 += v.x; S2 += v.y; }
    float mean = S1 * (1.f / 512.f);
    float var = S2 * (1.f / 512.f) - mean * mean;
    stat[tid * 2] = mean;
    stat[tid * 2 + 1] = rsqrtf(var + 1e-5f);
  }
  barrier_lds();
#pragma unroll
  for (int mt = 0; mt < 4; ++mt)
#pragma unroll
    for (int r = 0; r < 4; ++r) {
      int row = mt * 16 + 4 * qd + r;
      float mean = stat[row * 2], rstd = stat[row * 2 + 1];
#pragma unroll
      for (int ni = 0; ni < 4; ++ni) {
        int n = (4 * wv + ni) * 16 + ml;
        float x = (acc[mt][ni][r] - mean) * rstd * bf2f(Ps[pg * 512 + n]) + bf2f(Ps[pbe * 512 + n]);
        x = x > 0.f ? x : 0.01f * x;
        As[a_addr(row, n)] = f2bf(x);
      }
    }
  barrier_lds();  // As writes visible
}

// RK4 stage: k = acc + bout; h (f32) / ksum (bf16) in per-block global scratch
// (fragment-ordered, coalesced); writes next stage input y (bf16) into As.
static __device__ __forceinline__ void stage_epi64(floatx4 (&acc)[4][4], float* hblk,
                                                   unsigned short* kblk, unsigned short* As,
                                                   unsigned short* Yb, size_t m0,
                                                   const unsigned short* Ps, int stg, bool last,
                                                   int wv, int lane) {
  const int ml = lane & 15, qd = lane >> 4;
  barrier_lds();  // K-loop has no barriers: ensure all waves done reading As
#pragma unroll
  for (int mt = 0; mt < 4; ++mt)
#pragma unroll
    for (int ni = 0; ni < 4; ++ni) {
      int n = (4 * wv + ni) * 16 + ml;
      float bias = bf2f(Ps[7 * 512 + n]);
#pragma unroll
      for (int r = 0; r < 4; ++r) {
        float kv = acc[mt][ni][r] + bias;
        int ix = s_idx(wv, mt, ni, r, qd, ml);
        float hv = hblk[ix];
        float y;
        if (stg == 0) {
          kblk[ix] = f2bf(kv);
          y = hv + 0.125f * kv;
        } else if (stg == 1) {
          kblk[ix] = f2bf(bf2f(kblk[ix]) + 2.f * kv);
          y = hv + 0.125f * kv;
        } else if (stg == 2) {
          kblk[ix] = f2bf(bf2f(kblk[ix]) + 2.f * kv);
          y = hv + 0.25f * kv;
        } else {
          hv += (1.f / 24.f) * (bf2f(kblk[ix]) + kv);  // dt/6, dt=0.25
          hblk[ix] = hv;
          y = hv;
          if (last) Yb[(m0 + mt * 16 + 4 * qd + r) * 512 + n] = f2bf(y);
        }
        As[a_addr(mt * 16 + 4 * qd + r, n)] = f2bf(y);
      }
    }
  barrier_lds();  // As writes visible
}

__global__ __launch_bounds__(512) void ode_mega(
    unsigned short* Yb, const unsigned short* __restrict__ W1t,
    const unsigned short* __restrict__ W2t, const unsigned short* __restrict__ Wot,
    const float* __restrict__ b1, const float* __restrict__ tr, const float* __restrict__ g1,
    const float* __restrict__ be1, const float* __restrict__ b2, const float* __restrict__ g2,
    const float* __restrict__ be2, const float* __restrict__ bo, float* __restrict__ hbuf,
    unsigned short* __restrict__ kbuf) {
  __shared__ __align__(16) unsigned short As[32768];  // 64KB tiled A
  __shared__ __align__(16) unsigned short Ps[4096];   // 8KB params
  __shared__ float2 red[512];                         // 4KB
  __shared__ float stat[128];                         // 512B -> 78336B, 2 blocks/CU

  const int tid = threadIdx.x;
  const int lane = tid & 63;
  const int wv = tid >> 6;
  const int ml = lane & 15;
  const int qd = lane >> 4;
  float* hblk = hbuf + (size_t)blockIdx.x * 32768;
  unsigned short* kblk = kbuf + (size_t)blockIdx.x * 32768;

  // start weight prefetch immediately
  bf16x8 bb[2][4];
  bload(W1t, 0, wv, lane, bb[0]);
  bload(W1t, 1, wv, lane, bb[1]);

  {
    const float* srcs[8] = {b1, tr, g1, be1, b2, g2, be2, bo};
#pragma unroll
    for (int v = 0; v < 8; ++v) Ps[v * 512 + tid] = f2bf(srcs[v][tid]);
  }

  for (int grp = 0; grp < 2; ++grp) {  // persistent: 2 row-groups per block
    const size_t m0 = ((size_t)blockIdx.x + (size_t)grp * 512) * 64;
    // stage As: thread owns row r = tid>>3, chunks c = i*8 + (tid&7)
    {
      int r = tid >> 3;
#pragma unroll
      for (int i = 0; i < 8; ++i) {
        int c = i * 8 + (tid & 7);
        uint4 v = *(const uint4*)(Yb + (m0 + r) * 512 + c * 8);
        int dst = (((r >> 4) * 16 + (c >> 2)) * 4 + (c & 3)) * 128 + (r & 15) * 8;
        *(uint4*)(As + dst) = v;
      }
    }
    barrier_lds();
    // init h (f32, fragment order) from As
#pragma unroll
    for (int mt = 0; mt < 4; ++mt)
#pragma unroll
      for (int ni = 0; ni < 4; ++ni) {
        int n = (4 * wv + ni) * 16 + ml;
#pragma unroll
        for (int r = 0; r < 4; ++r)
          hblk[s_idx(wv, mt, ni, r, qd, ml)] = bf2f(As[a_addr(mt * 16 + 4 * qd + r, n)]);
      }

    for (int e = 0; e < 16; ++e) {  // 4 RK4 steps x 4 stages
      int stg = e & 3;
      float tval = 0.25f * (float)(e >> 2) + ((stg == 3) ? 0.25f : (stg ? 0.125f : 0.f));
      floatx4 acc[4][4];
      gemm64d(W1t, W2t, As, wv, lane, bb, acc);
      ln_epi64(acc, As, Ps, 0, 2, 3, true, tval, wv, lane, tid, red, stat);
      gemm64d(W2t, Wot, As, wv, lane, bb, acc);
      ln_epi64(acc, As, Ps, 4, 5, 6, false, 0.f, wv, lane, tid, red, stat);
      gemm64d(Wot, W1t, As, wv, lane, bb, acc);  // preloads next eval's W1
      stage_epi64(acc, hblk, kblk, As, Yb, m0, Ps, stg, e == 15, wv, lane);
    }
  }
}

// ---------------------------------------------------------------------------
// GRU step (unchanged): gi = y_t @ W_ih, gh = h_prev @ W_hh, gates.
// grid (32, 8): 32 rows x 64 gate-cols per block, 4 waves.
// ---------------------------------------------------------------------------
__global__ __launch_bounds__(256) void gru_step(
    const unsigned short* __restrict__ Yt, const float* __restrict__ hprev,
    float* __restrict__ hnew, const unsigned short* __restrict__ Wiht,
    const unsigned short* __restrict__ Whht, const float* __restrict__ bih,
    const float* __restrict__ bhh) {
  __shared__ __align__(16) unsigned short Ay[32 * BP];
  __shared__ __align__(16) unsigned short Ah[32 * BP];
  __shared__ __align__(16) unsigned short Bg[6 * 64 * BP];
  const int tid = threadIdx.x, lane = tid & 63, wv = tid >> 6;
  const int ml = lane & 15, qd = lane >> 4;
  const int m0 = blockIdx.x * 32;
  const int j0 = blockIdx.y * 64;

  floatx4 acc[2][6];
#pragma unroll
  for (int mi = 0; mi < 2; ++mi)
#pragma unroll
    for (int g = 0; g < 6; ++g) acc[mi][g] = 0.f;

  for (int kk = 0; kk < 16; ++kk) {
    __syncthreads();
#pragma unroll
    for (int c = 0; c < 7; ++c) {
      int id = c * 256 + tid;
      if (id < 128) {
        int r = id >> 2, kc = id & 3;
        *(uint4*)(Ay + r * BP + kc * 8) =
            *(const uint4*)(Yt + (size_t)(m0 + r) * 512 + kk * 32 + kc * 8);
      } else if (id < 256) {
        int id2 = id - 128;
        int r = id2 >> 2, kc = id2 & 3;
        const float* s = hprev + (size_t)(m0 + r) * 512 + kk * 32 + kc * 8;
        unsigned short o[8] __attribute__((aligned(16)));
#pragma unroll
        for (int j = 0; j < 8; ++j) o[j] = f2bf(s[j]);
        *(uint4*)(Ah + r * BP + kc * 8) = *(const uint4*)o;
      } else {
        int id2 = id - 256;
        int g = id2 >> 8;
        int rem = id2 & 255;
        int r = rem >> 2, kc = rem & 3;
        const unsigned short* mat = (g < 3) ? Wiht : Whht;
        int gate = (g < 3) ? g : (g - 3);
        *(uint4*)(Bg + g * (64 * BP) + r * BP + kc * 8) =
            *(const uint4*)(mat + (size_t)(gate * 512 + j0 + r) * 512 + kk * 32 + kc * 8);
      }
    }
    __syncthreads();
    bf16x8 ay[2], ah[2];
#pragma unroll
    for (int mi = 0; mi < 2; ++mi) {
      ay[mi] = *(const bf16x8*)&Ay[(16 * mi + ml) * BP + qd * 8];
      ah[mi] = *(const bf16x8*)&Ah[(16 * mi + ml) * BP + qd * 8];
    }
#pragma unroll
    for (int g = 0; g < 6; ++g) {
      bf16x8 b = *(const bf16x8*)&Bg[g * (64 * BP) + (16 * wv + ml) * BP + qd * 8];
#pragma unroll
      for (int mi = 0; mi < 2; ++mi)
        acc[mi][g] = __builtin_amdgcn_mfma_f32_16x16x32_bf16((g < 3) ? ay[mi] : ah[mi], b,
                                                             acc[mi][g], 0, 0, 0);
    }
  }
  int j = j0 + 16 * wv + ml;
  float bi_r = bih[j], bi_z = bih[512 + j], bi_n = bih[1024 + j];
  float bh_r = bhh[j], bh_z = bhh[512 + j], bh_n = bhh[1024 + j];
#pragma unroll
  for (int mi = 0; mi < 2; ++mi)
#pragma unroll
    for (int r = 0; r < 4; ++r) {
      size_t row = (size_t)(m0 + 16 * mi + 4 * qd + r);
      float rg = acc[mi][0][r] + bi_r + acc[mi][3][r] + bh_r;
      rg = 1.f / (1.f + __expf(-rg));
      float zg = acc[mi][1][r] + bi_z + acc[mi][4][r] + bh_z;
      zg = 1.f / (1.f + __expf(-zg));
      float ng = tanhf(acc[mi][2][r] + bi_n + rg * (acc[mi][5][r] + bh_n));
      float hp = hprev[row * 512 + j];
      hnew[row * 512 + j] = (1.f - zg) * ng + zg * hp;
    }
}

__global__ void zero_h(float* hf) {
  int i = blockIdx.x * 256 + threadIdx.x;
  hf[i] = 0.f;
}

// ---------------------------------------------------------------------------
extern "C" void kernel_launch(void* const* d_in, const int* in_sizes, int n_in,
                              void* d_out, int out_size, void* d_ws, size_t ws_size,
                              hipStream_t stream) {
  (void)in_sizes; (void)n_in; (void)out_size; (void)ws_size;
  const float* xs    = (const float*)d_in[0];
  const float* obsW  = (const float*)d_in[1];
  const float* obsb  = (const float*)d_in[2];
  const float* obsg  = (const float*)d_in[3];
  const float* obsbe = (const float*)d_in[4];
  const float* W1    = (const float*)d_in[5];
  const float* b1    = (const float*)d_in[6];
  const float* g1    = (const float*)d_in[7];
  const float* be1   = (const float*)d_in[8];
  const float* W2    = (const float*)d_in[9];
  const float* b2    = (const float*)d_in[10];
  const float* g2    = (const float*)d_in[11];
  const float* be2   = (const float*)d_in[12];
  const float* Wo    = (const float*)d_in[13];
  const float* bo    = (const float*)d_in[14];
  const float* Wih   = (const float*)d_in[15];
  const float* bih   = (const float*)d_in[16];
  const float* Whh   = (const float*)d_in[17];
  const float* bhh   = (const float*)d_in[18];

  char* p = (char*)d_ws;
  auto take = [&](size_t bytes) { char* q = p; p += (bytes + 255) & ~(size_t)255; return q; };
  unsigned short* W1t  = (unsigned short*)take((size_t)512 * 512 * 2);
  unsigned short* W2t  = (unsigned short*)take((size_t)512 * 512 * 2);
  unsigned short* Wot  = (unsigned short*)take((size_t)512 * 512 * 2);
  unsigned short* Wiht = (unsigned short*)take((size_t)1536 * 512 * 2);
  unsigned short* Whht = (unsigned short*)take((size_t)1536 * 512 * 2);
  float* hf0 = (float*)take((size_t)1024 * 512 * 4);
  float* hf1 = (float*)take((size_t)1024 * 512 * 4);
  unsigned short* Yb = (unsigned short*)take((size_t)65536 * 512 * 2);
  float* hode = (float*)take((size_t)512 * 32768 * 4);           // 64MB RK4 h state
  unsigned short* kode = (unsigned short*)take((size_t)512 * 32768 * 2);  // 32MB RK4 ksum

  dim3 tb(32, 8);
  tile_weight<<<128, 256, 0, stream>>>(W1, W1t);  // first 512 of 513 rows
  tile_weight<<<128, 256, 0, stream>>>(W2, W2t);
  tile_weight<<<128, 256, 0, stream>>>(Wo, Wot);
  transpose_f2b<<<dim3(48, 16), tb, 0, stream>>>(Wih, Wiht, 512, 1536);
  transpose_f2b<<<dim3(48, 16), tb, 0, stream>>>(Whh, Whht, 512, 1536);

  obs_embed<<<16384, 256, 0, stream>>>(xs, obsW, obsb, obsg, obsbe, Yb);

  // tr = W1 row 512 (time row), folded into layer-1 bias per eval.
  ode_mega<<<512, 512, 0, stream>>>(Yb, W1t, W2t, Wot, b1, W1 + 512 * 512, g1, be1, b2, g2,
                                    be2, bo, hode, kode);

  zero_h<<<2048, 256, 0, stream>>>(hf0);
  float* hf[2] = {hf0, hf1};
  for (int t = 0; t < 64; ++t) {
    int s = t & 1, d = s ^ 1;
    float* hn = (t == 63) ? (float*)d_out : hf[d];
    gru_step<<<dim3(32, 8), 256, 0, stream>>>(Yb + (size_t)t * 1024 * 512, hf[s], hn, Wiht, Whht,
                                              bih, bhh);
  }
}

// Round 10
// 4489.082 us; speedup vs baseline: 3.0848x; 1.3154x over previous
//
#include <hip/hip_runtime.h>
#include <stdint.h>

// ---------------------------------------------------------------------------
// ODE-RNN encoder, f32 I/O, bf16 MFMA internals.
// R10: test the measured register-budget law budget = 131072/(2*threads):
// 512thr->128 (R4-R9), 1024thr->64 (R6/R8). Extrapolation: 256thr->256.
// ode_mega goes to 256 threads / 32-row blocks so the full RK4 state fits in
// registers again: acc[2][8] 64 + h[2][8][4] 64 + ks packed 32 + bb dbuf 64
// ~= 232 <= 256. No global h/ks, no spills, B global->VGPR dbuf, K-loop
// barrier-free, epilogue barriers lgkm-only. LDS 41.5KB -> 2 blocks/CU.
// ---------------------------------------------------------------------------

typedef __bf16 bf16x8 __attribute__((ext_vector_type(8)));
typedef float floatx4 __attribute__((ext_vector_type(4)));

#define BP 40  // gru_step padded B row (ushorts)

static __device__ __forceinline__ float bf2f(unsigned short u) {
  union { unsigned int u32; float f; } c;
  c.u32 = ((unsigned int)u) << 16;
  return c.f;
}
static __device__ __forceinline__ unsigned short f2bf(float f) {
  union { __bf16 h; unsigned short u; } c;
  c.h = (__bf16)f;  // RNE
  return c.u;
}

// LDS-only barrier: does NOT drain vmcnt, so global prefetches stay in flight.
static __device__ __forceinline__ void barrier_lds() {
  __asm__ volatile("s_waitcnt lgkmcnt(0)\n\ts_barrier" ::: "memory");
}

// ---------------------------------------------------------------------------
// tile_weight: W (K=512 x N=512, f32 row-major) -> bf16 tiled
// [kk(16)][nt(32)][qd(4)][ml(16)][8]; element (kk,nt,qd,ml,j) = W[kk*32+qd*8+j][nt*16+ml]
// ---------------------------------------------------------------------------
__global__ void tile_weight(const float* __restrict__ src, unsigned short* __restrict__ dst) {
  int t = blockIdx.x * 256 + threadIdx.x;  // 0..32767
  int ml = t & 15, qd = (t >> 4) & 3;
  int nt = (t >> 6) & 31, kk = t >> 11;
  int n = nt * 16 + ml;
  int k0 = kk * 32 + qd * 8;
  unsigned short o[8] __attribute__((aligned(16)));
#pragma unroll
  for (int j = 0; j < 8; ++j) o[j] = f2bf(src[(size_t)(k0 + j) * 512 + n]);
  *(uint4*)(dst + (size_t)t * 8) = *(const uint4*)o;
}

// ---------------------------------------------------------------------------
// transpose + f32->bf16 (GRU weights, [n][k] flat layout)
// ---------------------------------------------------------------------------
__global__ void transpose_f2b(const float* __restrict__ src, unsigned short* __restrict__ dst,
                              int R, int C) {
  __shared__ float t[32][33];
  int c0 = blockIdx.x * 32, r0 = blockIdx.y * 32;
  int tx = threadIdx.x, ty = threadIdx.y;  // 32 x 8
#pragma unroll
  for (int i = 0; i < 32; i += 8) t[ty + i][tx] = src[(size_t)(r0 + ty + i) * C + c0 + tx];
  __syncthreads();
#pragma unroll
  for (int i = 0; i < 32; i += 8) dst[(size_t)(c0 + ty + i) * R + r0 + tx] = f2bf(t[tx][ty + i]);
}

// ---------------------------------------------------------------------------
// obs embed: y = leaky(LN(xs @ W + b)) (f32 in, bf16 out), one wave per row
// ---------------------------------------------------------------------------
__global__ __launch_bounds__(256) void obs_embed(
    const float* __restrict__ xs, const float* __restrict__ W,
    const float* __restrict__ bias, const float* __restrict__ gam,
    const float* __restrict__ bet, unsigned short* __restrict__ Y) {
  __shared__ float Wl[4096];
  const int tid = threadIdx.x, lane = tid & 63, wv = tid >> 6;
#pragma unroll
  for (int i = 0; i < 16; ++i) Wl[i * 256 + tid] = W[i * 256 + tid];
  __syncthreads();
  size_t row = (size_t)blockIdx.x * 4 + wv;
  float xf[8];
  {
    const float* xp = xs + row * 8;
#pragma unroll
    for (int k = 0; k < 8; ++k) xf[k] = xp[k];
  }
  int n0 = lane * 8;
  float a[8];
#pragma unroll
  for (int j = 0; j < 8; ++j) a[j] = bias[n0 + j];
#pragma unroll
  for (int k = 0; k < 8; ++k)
#pragma unroll
    for (int j = 0; j < 8; ++j) a[j] += xf[k] * Wl[k * 512 + n0 + j];
  float s1 = 0.f, s2 = 0.f;
#pragma unroll
  for (int j = 0; j < 8; ++j) { s1 += a[j]; s2 += a[j] * a[j]; }
#pragma unroll
  for (int off = 1; off < 64; off <<= 1) { s1 += __shfl_xor(s1, off); s2 += __shfl_xor(s2, off); }
  float mean = s1 * (1.f / 512.f);
  float rstd = rsqrtf(s2 * (1.f / 512.f) - mean * mean + 1e-5f);
  unsigned short o[8] __attribute__((aligned(16)));
#pragma unroll
  for (int j = 0; j < 8; ++j) {
    float v = (a[j] - mean) * rstd * gam[n0 + j] + bet[n0 + j];
    v = v > 0.f ? v : 0.01f * v;
    o[j] = f2bf(v);
  }
  *(uint4*)(Y + row * 512 + n0) = *(const uint4*)o;
}

// ---------------------------------------------------------------------------
// ODE megakernel. A (32x512) resident in tiled LDS [mt][kk][qd][ml][8];
// 4 waves, each owning M=32 (2 mt) x N=128 (nt = wv*8 .. wv*8+7).
// B fragments stream global->VGPR dbuf; K-loop barrier-free.
// ---------------------------------------------------------------------------

// element (row, n) address in tiled A (ushort index), row < 32
static __device__ __forceinline__ int a_addr(int row, int n) {
  return (((row >> 4) * 16 + (n >> 5)) * 4 + ((n >> 3) & 3)) * 128 + (row & 15) * 8 + (n & 7);
}

static __device__ __forceinline__ void bload8(const unsigned short* __restrict__ Wt, int kk,
                                              int wv, int lane, bf16x8 (&b)[8]) {
#pragma unroll
  for (int j = 0; j < 8; ++j)
    b[j] = *(const bf16x8*)(Wt + ((size_t)kk * 32 + 8 * wv + j) * 512 + (size_t)lane * 8);
}

// bb must hold Wt slabs {0,1} on entry; holds Wnext slabs {0,1} on exit.
static __device__ __forceinline__ void gemm32(const unsigned short* __restrict__ Wt,
                                              const unsigned short* __restrict__ Wnext,
                                              const unsigned short* As, int wv, int lane,
                                              bf16x8 (&bb)[2][8], floatx4 (&acc)[2][8]) {
#pragma unroll
  for (int mi = 0; mi < 2; ++mi)
#pragma unroll
    for (int j = 0; j < 8; ++j) acc[mi][j] = 0.f;
#pragma unroll 2
  for (int kk = 0; kk < 16; ++kk) {  // unroll 2 (dbuf parity), NOT full (R5-R8 lesson)
    bf16x8 a[2];
#pragma unroll
    for (int mi = 0; mi < 2; ++mi) a[mi] = *(const bf16x8*)&As[(mi * 16 + kk) * 512 + lane * 8];
#pragma unroll
    for (int mi = 0; mi < 2; ++mi)
#pragma unroll
      for (int j = 0; j < 8; ++j)
        acc[mi][j] =
            __builtin_amdgcn_mfma_f32_16x16x32_bf16(a[mi], bb[kk & 1][j], acc[mi][j], 0, 0, 0);
    // refill the just-consumed slot: kk+2 of this weight, or next weight's 0/1
    if (kk < 14) bload8(Wt, kk + 2, wv, lane, bb[kk & 1]);
    else bload8(Wnext, kk - 14, wv, lane, bb[kk & 1]);
  }
}

// LN + leaky epilogue; writes bf16 result into tiled As.
static __device__ __forceinline__ void ln_epi32(floatx4 (&acc)[2][8], unsigned short* As,
                                                const unsigned short* Ps, int pb, int pg, int pbe,
                                                bool addt, float tval, int wv, int lane, int tid,
                                                float2* red, float* stat) {
  const int ml = lane & 15, qd = lane >> 4;
#pragma unroll
  for (int j = 0; j < 8; ++j) {
    int n = (8 * wv + j) * 16 + ml;
    float bias = bf2f(Ps[pb * 512 + n]);
    if (addt) bias += tval * bf2f(Ps[512 + n]);
#pragma unroll
    for (int mi = 0; mi < 2; ++mi)
#pragma unroll
      for (int r = 0; r < 4; ++r) acc[mi][j][r] += bias;
  }
#pragma unroll
  for (int mi = 0; mi < 2; ++mi)
#pragma unroll
    for (int r = 0; r < 4; ++r) {
      float s1 = 0.f, s2 = 0.f;
#pragma unroll
      for (int j = 0; j < 8; ++j) { float x = acc[mi][j][r]; s1 += x; s2 += x * x; }
#pragma unroll
      for (int off = 1; off < 16; off <<= 1) { s1 += __shfl_xor(s1, off); s2 += __shfl_xor(s2, off); }
      if (ml == 0) red[(mi * 16 + 4 * qd + r) * 4 + wv] = make_float2(s1, s2);
    }
  barrier_lds();  // red visible; all waves past their As a-frag reads
  if (tid < 32) {
    float S1 = 0.f, S2 = 0.f;
#pragma unroll
    for (int w = 0; w < 4; ++w) { float2 v = red[tid * 4 + w]; S1 += v.x; S2 += v.y; }
    float mean = S1 * (1.f / 512.f);
    float var = S2 * (1.f / 512.f) - mean * mean;
    stat[tid * 2] = mean;
    stat[tid * 2 + 1] = rsqrtf(var + 1e-5f);
  }
  barrier_lds();
#pragma unroll
  for (int mi = 0; mi < 2; ++mi)
#pragma unroll
    for (int r = 0; r < 4; ++r) {
      int row = mi * 16 + 4 * qd + r;
      float mean = stat[row * 2], rstd = stat[row * 2 + 1];
#pragma unroll
      for (int j = 0; j < 8; ++j) {
        int n = (8 * wv + j) * 16 + ml;
        float x = (acc[mi][j][r] - mean) * rstd * bf2f(Ps[pg * 512 + n]) + bf2f(Ps[pbe * 512 + n]);
        x = x > 0.f ? x : 0.01f * x;
        As[a_addr(row, n)] = f2bf(x);
      }
    }
  barrier_lds();  // As writes visible
}

// RK4 stage: k = acc + bout; h fp32 regs, ksum packed bf16 pairs; writes y
// into As; on the final stage also writes h_ode to Yb.
static __device__ __forceinline__ void stage_epi32(floatx4 (&acc)[2][8], float (&h)[2][8][4],
                                                   unsigned int (&ks)[2][8][2], unsigned short* As,
                                                   unsigned short* Yb, size_t m0,
                                                   const unsigned short* Ps, int stg, bool last,
                                                   int wv, int lane) {
  const int ml = lane & 15, qd = lane >> 4;
  barrier_lds();  // K-loop has no barriers: ensure all waves done reading As
#pragma unroll
  for (int mi = 0; mi < 2; ++mi)
#pragma unroll
    for (int j = 0; j < 8; ++j) {
      int n = (8 * wv + j) * 16 + ml;
      float bias = bf2f(Ps[7 * 512 + n]);
#pragma unroll
      for (int rp = 0; rp < 2; ++rp) {
        float kv0 = acc[mi][j][2 * rp] + bias;
        float kv1 = acc[mi][j][2 * rp + 1] + bias;
        unsigned int pk = ks[mi][j][rp];
        float s0 = bf2f((unsigned short)(pk & 0xffffu));
        float s1 = bf2f((unsigned short)(pk >> 16));
        float h0 = h[mi][j][2 * rp], h1 = h[mi][j][2 * rp + 1];
        float y0, y1;
        if (stg == 0)      { s0 = kv0;        s1 = kv1;        y0 = h0 + 0.125f * kv0; y1 = h1 + 0.125f * kv1; }
        else if (stg == 1) { s0 += 2.f * kv0; s1 += 2.f * kv1; y0 = h0 + 0.125f * kv0; y1 = h1 + 0.125f * kv1; }
        else if (stg == 2) { s0 += 2.f * kv0; s1 += 2.f * kv1; y0 = h0 + 0.25f * kv0;  y1 = h1 + 0.25f * kv1; }
        else {
          h0 += (1.f / 24.f) * (s0 + kv0);  // dt/6, dt=0.25
          h1 += (1.f / 24.f) * (s1 + kv1);
          h[mi][j][2 * rp] = h0; h[mi][j][2 * rp + 1] = h1;
          y0 = h0; y1 = h1;
        }
        ks[mi][j][rp] = (unsigned int)f2bf(s0) | ((unsigned int)f2bf(s1) << 16);
        int row = mi * 16 + 4 * qd + 2 * rp;
        As[a_addr(row, n)] = f2bf(y0);
        As[a_addr(row + 1, n)] = f2bf(y1);
        if (last && stg == 3) {
          Yb[(m0 + row) * 512 + n] = f2bf(y0);
          Yb[(m0 + row + 1) * 512 + n] = f2bf(y1);
        }
      }
    }
  barrier_lds();  // As writes visible
}

__global__ __launch_bounds__(256) void ode_mega(
    unsigned short* Yb, const unsigned short* __restrict__ W1t,
    const unsigned short* __restrict__ W2t, const unsigned short* __restrict__ Wot,
    const float* __restrict__ b1, const float* __restrict__ tr, const float* __restrict__ g1,
    const float* __restrict__ be1, const float* __restrict__ b2, const float* __restrict__ g2,
    const float* __restrict__ be2, const float* __restrict__ bo) {
  __shared__ __align__(16) unsigned short As[16384];  // 32KB tiled A (32 rows)
  __shared__ __align__(16) unsigned short Ps[4096];   // 8KB params
  __shared__ float2 red[128];                         // 1KB: 32 rows x 4 waves
  __shared__ float stat[64];                          // 256B -> ~41.5KB, 2 blocks/CU

  const int tid = threadIdx.x;
  const int lane = tid & 63;
  const int wv = tid >> 6;  // 0..3
  const int ml = lane & 15;
  const int qd = lane >> 4;
  const size_t m0 = (size_t)blockIdx.x * 32;

  // start weight prefetch immediately
  bf16x8 bb[2][8];
  bload8(W1t, 0, wv, lane, bb[0]);
  bload8(W1t, 1, wv, lane, bb[1]);

  {
    const float* srcs[8] = {b1, tr, g1, be1, b2, g2, be2, bo};
#pragma unroll
    for (int v = 0; v < 8; ++v) {
      Ps[v * 512 + tid] = f2bf(srcs[v][tid]);
      Ps[v * 512 + 256 + tid] = f2bf(srcs[v][256 + tid]);
    }
  }
  // stage As: thread owns row r = tid>>3, chunks c = i*8 + (tid&7)
  {
    int r = tid >> 3;  // 0..31
#pragma unroll
    for (int i = 0; i < 8; ++i) {
      int c = i * 8 + (tid & 7);
      uint4 v = *(const uint4*)(Yb + (m0 + r) * 512 + c * 8);
      int dst = (((r >> 4) * 16 + (c >> 2)) * 4 + (c & 3)) * 128 + (r & 15) * 8;
      *(uint4*)(As + dst) = v;
    }
  }
  barrier_lds();

  float h[2][8][4];          // fp32 ODE state, MFMA C-layout
  unsigned int ks[2][8][2];  // RK4 ksum, packed bf16 pairs
#pragma unroll
  for (int mi = 0; mi < 2; ++mi)
#pragma unroll
    for (int j = 0; j < 8; ++j) {
      ks[mi][j][0] = 0u; ks[mi][j][1] = 0u;
      int n = (8 * wv + j) * 16 + ml;
#pragma unroll
      for (int r = 0; r < 4; ++r) h[mi][j][r] = bf2f(As[a_addr(mi * 16 + 4 * qd + r, n)]);
    }

  for (int e = 0; e < 16; ++e) {  // 4 RK4 steps x 4 stages
    int stg = e & 3;
    float tval = 0.25f * (float)(e >> 2) + ((stg == 3) ? 0.25f : (stg ? 0.125f : 0.f));
    floatx4 acc[2][8];
    gemm32(W1t, W2t, As, wv, lane, bb, acc);
    ln_epi32(acc, As, Ps, 0, 2, 3, true, tval, wv, lane, tid, red, stat);
    gemm32(W2t, Wot, As, wv, lane, bb, acc);
    ln_epi32(acc, As, Ps, 4, 5, 6, false, 0.f, wv, lane, tid, red, stat);
    gemm32(Wot, W1t, As, wv, lane, bb, acc);  // preloads next eval's W1
    stage_epi32(acc, h, ks, As, Yb, m0, Ps, stg, e == 15, wv, lane);
  }
}

// ---------------------------------------------------------------------------
// GRU step (unchanged): gi = y_t @ W_ih, gh = h_prev @ W_hh, gates.
// grid (32, 8): 32 rows x 64 gate-cols per block, 4 waves.
// ---------------------------------------------------------------------------
__global__ __launch_bounds__(256) void gru_step(
    const unsigned short* __restrict__ Yt, const float* __restrict__ hprev,
    float* __restrict__ hnew, const unsigned short* __restrict__ Wiht,
    const unsigned short* __restrict__ Whht, const float* __restrict__ bih,
    const float* __restrict__ bhh) {
  __shared__ __align__(16) unsigned short Ay[32 * BP];
  __shared__ __align__(16) unsigned short Ah[32 * BP];
  __shared__ __align__(16) unsigned short Bg[6 * 64 * BP];
  const int tid = threadIdx.x, lane = tid & 63, wv = tid >> 6;
  const int ml = lane & 15, qd = lane >> 4;
  const int m0 = blockIdx.x * 32;
  const int j0 = blockIdx.y * 64;

  floatx4 acc[2][6];
#pragma unroll
  for (int mi = 0; mi < 2; ++mi)
#pragma unroll
    for (int g = 0; g < 6; ++g) acc[mi][g] = 0.f;

  for (int kk = 0; kk < 16; ++kk) {
    __syncthreads();
#pragma unroll
    for (int c = 0; c < 7; ++c) {
      int id = c * 256 + tid;
      if (id < 128) {
        int r = id >> 2, kc = id & 3;
        *(uint4*)(Ay + r * BP + kc * 8) =
            *(const uint4*)(Yt + (size_t)(m0 + r) * 512 + kk * 32 + kc * 8);
      } else if (id < 256) {
        int id2 = id - 128;
        int r = id2 >> 2, kc = id2 & 3;
        const float* s = hprev + (size_t)(m0 + r) * 512 + kk * 32 + kc * 8;
        unsigned short o[8] __attribute__((aligned(16)));
#pragma unroll
        for (int j = 0; j < 8; ++j) o[j] = f2bf(s[j]);
        *(uint4*)(Ah + r * BP + kc * 8) = *(const uint4*)o;
      } else {
        int id2 = id - 256;
        int g = id2 >> 8;
        int rem = id2 & 255;
        int r = rem >> 2, kc = rem & 3;
        const unsigned short* mat = (g < 3) ? Wiht : Whht;
        int gate = (g < 3) ? g : (g - 3);
        *(uint4*)(Bg + g * (64 * BP) + r * BP + kc * 8) =
            *(const uint4*)(mat + (size_t)(gate * 512 + j0 + r) * 512 + kk * 32 + kc * 8);
      }
    }
    __syncthreads();
    bf16x8 ay[2], ah[2];
#pragma unroll
    for (int mi = 0; mi < 2; ++mi) {
      ay[mi] = *(const bf16x8*)&Ay[(16 * mi + ml) * BP + qd * 8];
      ah[mi] = *(const bf16x8*)&Ah[(16 * mi + ml) * BP + qd * 8];
    }
#pragma unroll
    for (int g = 0; g < 6; ++g) {
      bf16x8 b = *(const bf16x8*)&Bg[g * (64 * BP) + (16 * wv + ml) * BP + qd * 8];
#pragma unroll
      for (int mi = 0; mi < 2; ++mi)
        acc[mi][g] = __builtin_amdgcn_mfma_f32_16x16x32_bf16((g < 3) ? ay[mi] : ah[mi], b,
                                                             acc[mi][g], 0, 0, 0);
    }
  }
  int j = j0 + 16 * wv + ml;
  float bi_r = bih[j], bi_z = bih[512 + j], bi_n = bih[1024 + j];
  float bh_r = bhh[j], bh_z = bhh[512 + j], bh_n = bhh[1024 + j];
#pragma unroll
  for (int mi = 0; mi < 2; ++mi)
#pragma unroll
    for (int r = 0; r < 4; ++r) {
      size_t row = (size_t)(m0 + 16 * mi + 4 * qd + r);
      float rg = acc[mi][0][r] + bi_r + acc[mi][3][r] + bh_r;
      rg = 1.f / (1.f + __expf(-rg));
      float zg = acc[mi][1][r] + bi_z + acc[mi][4][r] + bh_z;
      zg = 1.f / (1.f + __expf(-zg));
      float ng = tanhf(acc[mi][2][r] + bi_n + rg * (acc[mi][5][r] + bh_n));
      float hp = hprev[row * 512 + j];
      hnew[row * 512 + j] = (1.f - zg) * ng + zg * hp;
    }
}

__global__ void zero_h(float* hf) {
  int i = blockIdx.x * 256 + threadIdx.x;
  hf[i] = 0.f;
}

// ---------------------------------------------------------------------------
extern "C" void kernel_launch(void* const* d_in, const int* in_sizes, int n_in,
                              void* d_out, int out_size, void* d_ws, size_t ws_size,
                              hipStream_t stream) {
  (void)in_sizes; (void)n_in; (void)out_size; (void)ws_size;
  const float* xs    = (const float*)d_in[0];
  const float* obsW  = (const float*)d_in[1];
  const float* obsb  = (const float*)d_in[2];
  const float* obsg  = (const float*)d_in[3];
  const float* obsbe = (const float*)d_in[4];
  const float* W1    = (const float*)d_in[5];
  const float* b1    = (const float*)d_in[6];
  const float* g1    = (const float*)d_in[7];
  const float* be1   = (const float*)d_in[8];
  const float* W2    = (const float*)d_in[9];
  const float* b2    = (const float*)d_in[10];
  const float* g2    = (const float*)d_in[11];
  const float* be2   = (const float*)d_in[12];
  const float* Wo    = (const float*)d_in[13];
  const float* bo    = (const float*)d_in[14];
  const float* Wih   = (const float*)d_in[15];
  const float* bih   = (const float*)d_in[16];
  const float* Whh   = (const float*)d_in[17];
  const float* bhh   = (const float*)d_in[18];

  char* p = (char*)d_ws;
  auto take = [&](size_t bytes) { char* q = p; p += (bytes + 255) & ~(size_t)255; return q; };
  unsigned short* W1t  = (unsigned short*)take((size_t)512 * 512 * 2);
  unsigned short* W2t  = (unsigned short*)take((size_t)512 * 512 * 2);
  unsigned short* Wot  = (unsigned short*)take((size_t)512 * 512 * 2);
  unsigned short* Wiht = (unsigned short*)take((size_t)1536 * 512 * 2);
  unsigned short* Whht = (unsigned short*)take((size_t)1536 * 512 * 2);
  float* hf0 = (float*)take((size_t)1024 * 512 * 4);
  float* hf1 = (float*)take((size_t)1024 * 512 * 4);
  unsigned short* Yb = (unsigned short*)take((size_t)65536 * 512 * 2);

  dim3 tb(32, 8);
  tile_weight<<<128, 256, 0, stream>>>(W1, W1t);  // first 512 of 513 rows
  tile_weight<<<128, 256, 0, stream>>>(W2, W2t);
  tile_weight<<<128, 256, 0, stream>>>(Wo, Wot);
  transpose_f2b<<<dim3(48, 16), tb, 0, stream>>>(Wih, Wiht, 512, 1536);
  transpose_f2b<<<dim3(48, 16), tb, 0, stream>>>(Whh, Whht, 512, 1536);

  obs_embed<<<16384, 256, 0, stream>>>(xs, obsW, obsb, obsg, obsbe, Yb);

  // tr = W1 row 512 (time row), folded into layer-1 bias per eval.
  ode_mega<<<2048, 256, 0, stream>>>(Yb, W1t, W2t, Wot, b1, W1 + 512 * 512, g1, be1, b2, g2,
                                     be2, bo);

  zero_h<<<2048, 256, 0, stream>>>(hf0);
  float* hf[2] = {hf0, hf1};
  for (int t = 0; t < 64; ++t) {
    int s = t & 1, d = s ^ 1;
    float* hn = (t == 63) ? (float*)d_out : hf[d];
    gru_step<<<dim3(32, 8), 256, 0, stream>>>(Yb + (size_t)t * 1024 * 512, hf[s], hn, Wiht, Whht,
                                              bih, bhh);
  }
}

// Round 11
// 4451.674 us; speedup vs baseline: 3.1107x; 1.0084x over previous
//
#include <hip/hip_runtime.h>
#include <stdint.h>

// ---------------------------------------------------------------------------
// ODE-RNN encoder, f32 I/O, bf16 MFMA internals.
// R11 = R10 (256-thr ode_mega, full state in 228 regs, zero spills) with the
// B-stream pipeline deepened: half-slab (4-frag) groups in a depth-4 circular
// VGPR buffer (bb[4][4] = 64 regs, same count as R10's bb[2][8]) -> 3-group
// prefetch lead ~230 cyc > ~200 cyc L2 latency. R10's 1-slab lead (~154 cyc)
// left a stall every kk => MfmaUtil 21%, 40% idle.
// ---------------------------------------------------------------------------

typedef __bf16 bf16x8 __attribute__((ext_vector_type(8)));
typedef float floatx4 __attribute__((ext_vector_type(4)));

#define BP 40  // gru_step padded B row (ushorts)

static __device__ __forceinline__ float bf2f(unsigned short u) {
  union { unsigned int u32; float f; } c;
  c.u32 = ((unsigned int)u) << 16;
  return c.f;
}
static __device__ __forceinline__ unsigned short f2bf(float f) {
  union { __bf16 h; unsigned short u; } c;
  c.h = (__bf16)f;  // RNE
  return c.u;
}

// LDS-only barrier: does NOT drain vmcnt, so global prefetches stay in flight.
static __device__ __forceinline__ void barrier_lds() {
  __asm__ volatile("s_waitcnt lgkmcnt(0)\n\ts_barrier" ::: "memory");
}

// ---------------------------------------------------------------------------
// tile_weight: W (K=512 x N=512, f32 row-major) -> bf16 tiled
// [kk(16)][nt(32)][qd(4)][ml(16)][8]; element (kk,nt,qd,ml,j) = W[kk*32+qd*8+j][nt*16+ml]
// ---------------------------------------------------------------------------
__global__ void tile_weight(const float* __restrict__ src, unsigned short* __restrict__ dst) {
  int t = blockIdx.x * 256 + threadIdx.x;  // 0..32767
  int ml = t & 15, qd = (t >> 4) & 3;
  int nt = (t >> 6) & 31, kk = t >> 11;
  int n = nt * 16 + ml;
  int k0 = kk * 32 + qd * 8;
  unsigned short o[8] __attribute__((aligned(16)));
#pragma unroll
  for (int j = 0; j < 8; ++j) o[j] = f2bf(src[(size_t)(k0 + j) * 512 + n]);
  *(uint4*)(dst + (size_t)t * 8) = *(const uint4*)o;
}

// ---------------------------------------------------------------------------
// transpose + f32->bf16 (GRU weights, [n][k] flat layout)
// ---------------------------------------------------------------------------
__global__ void transpose_f2b(const float* __restrict__ src, unsigned short* __restrict__ dst,
                              int R, int C) {
  __shared__ float t[32][33];
  int c0 = blockIdx.x * 32, r0 = blockIdx.y * 32;
  int tx = threadIdx.x, ty = threadIdx.y;  // 32 x 8
#pragma unroll
  for (int i = 0; i < 32; i += 8) t[ty + i][tx] = src[(size_t)(r0 + ty + i) * C + c0 + tx];
  __syncthreads();
#pragma unroll
  for (int i = 0; i < 32; i += 8) dst[(size_t)(c0 + ty + i) * R + r0 + tx] = f2bf(t[tx][ty + i]);
}

// ---------------------------------------------------------------------------
// obs embed: y = leaky(LN(xs @ W + b)) (f32 in, bf16 out), one wave per row
// ---------------------------------------------------------------------------
__global__ __launch_bounds__(256) void obs_embed(
    const float* __restrict__ xs, const float* __restrict__ W,
    const float* __restrict__ bias, const float* __restrict__ gam,
    const float* __restrict__ bet, unsigned short* __restrict__ Y) {
  __shared__ float Wl[4096];
  const int tid = threadIdx.x, lane = tid & 63, wv = tid >> 6;
#pragma unroll
  for (int i = 0; i < 16; ++i) Wl[i * 256 + tid] = W[i * 256 + tid];
  __syncthreads();
  size_t row = (size_t)blockIdx.x * 4 + wv;
  float xf[8];
  {
    const float* xp = xs + row * 8;
#pragma unroll
    for (int k = 0; k < 8; ++k) xf[k] = xp[k];
  }
  int n0 = lane * 8;
  float a[8];
#pragma unroll
  for (int j = 0; j < 8; ++j) a[j] = bias[n0 + j];
#pragma unroll
  for (int k = 0; k < 8; ++k)
#pragma unroll
    for (int j = 0; j < 8; ++j) a[j] += xf[k] * Wl[k * 512 + n0 + j];
  float s1 = 0.f, s2 = 0.f;
#pragma unroll
  for (int j = 0; j < 8; ++j) { s1 += a[j]; s2 += a[j] * a[j]; }
#pragma unroll
  for (int off = 1; off < 64; off <<= 1) { s1 += __shfl_xor(s1, off); s2 += __shfl_xor(s2, off); }
  float mean = s1 * (1.f / 512.f);
  float rstd = rsqrtf(s2 * (1.f / 512.f) - mean * mean + 1e-5f);
  unsigned short o[8] __attribute__((aligned(16)));
#pragma unroll
  for (int j = 0; j < 8; ++j) {
    float v = (a[j] - mean) * rstd * gam[n0 + j] + bet[n0 + j];
    v = v > 0.f ? v : 0.01f * v;
    o[j] = f2bf(v);
  }
  *(uint4*)(Y + row * 512 + n0) = *(const uint4*)o;
}

// ---------------------------------------------------------------------------
// ODE megakernel. A (32x512) resident in tiled LDS [mt][kk][qd][ml][8];
// 4 waves, each owning M=32 (2 mi) x N=128 (nt = wv*8 .. wv*8+7).
// B: half-slab groups (4 frags) global->VGPR, depth-4 circular buffer.
// K-loop barrier-free; epilogue barriers lgkm-only.
// ---------------------------------------------------------------------------

// element (row, n) address in tiled A (ushort index), row < 32
static __device__ __forceinline__ int a_addr(int row, int n) {
  return (((row >> 4) * 16 + (n >> 5)) * 4 + ((n >> 3) & 3)) * 128 + (row & 15) * 8 + (n & 7);
}

// group g (0..31): kk = g>>1, frags j = (g&1)*4 .. (g&1)*4+3 of this wave's 8
static __device__ __forceinline__ void bload4(const unsigned short* __restrict__ Wt, int g,
                                              int wv, int lane, bf16x8 (&b)[4]) {
  int col0 = (g >> 1) * 32 + 8 * wv + (g & 1) * 4;
#pragma unroll
  for (int j = 0; j < 4; ++j)
    b[j] = *(const bf16x8*)(Wt + ((size_t)col0 + j) * 512 + (size_t)lane * 8);
}

// bb holds Wt groups {0,1,2,3} on entry; holds Wnext groups {0,1,2,3} on exit.
static __device__ __forceinline__ void gemm32(const unsigned short* __restrict__ Wt,
                                              const unsigned short* __restrict__ Wnext,
                                              const unsigned short* As, int wv, int lane,
                                              bf16x8 (&bb)[4][4], floatx4 (&acc)[2][8]) {
#pragma unroll
  for (int mi = 0; mi < 2; ++mi)
#pragma unroll
    for (int j = 0; j < 8; ++j) acc[mi][j] = 0.f;
  bf16x8 a[2];
#pragma unroll 4
  for (int g = 0; g < 32; ++g) {  // period-4 unroll: g&3 / g&1 static, ranges short
    int kk = g >> 1, half = g & 1;
    if (half == 0) {
#pragma unroll
      for (int mi = 0; mi < 2; ++mi)
        a[mi] = *(const bf16x8*)&As[(mi * 16 + kk) * 512 + lane * 8];
    }
#pragma unroll
    for (int mi = 0; mi < 2; ++mi)
#pragma unroll
      for (int j = 0; j < 4; ++j)
        acc[mi][half * 4 + j] = __builtin_amdgcn_mfma_f32_16x16x32_bf16(
            a[mi], bb[g & 3][j], acc[mi][half * 4 + j], 0, 0, 0);
    // refill just-consumed slot with group g+4 (3-group lead > L2 latency)
    if (g < 28) bload4(Wt, g + 4, wv, lane, bb[g & 3]);
    else bload4(Wnext, g - 28, wv, lane, bb[g & 3]);
  }
}

// LN + leaky epilogue; writes bf16 result into tiled As.
static __device__ __forceinline__ void ln_epi32(floatx4 (&acc)[2][8], unsigned short* As,
                                                const unsigned short* Ps, int pb, int pg, int pbe,
                                                bool addt, float tval, int wv, int lane, int tid,
                                                float2* red, float* stat) {
  const int ml = lane & 15, qd = lane >> 4;
#pragma unroll
  for (int j = 0; j < 8; ++j) {
    int n = (8 * wv + j) * 16 + ml;
    float bias = bf2f(Ps[pb * 512 + n]);
    if (addt) bias += tval * bf2f(Ps[512 + n]);
#pragma unroll
    for (int mi = 0; mi < 2; ++mi)
#pragma unroll
      for (int r = 0; r < 4; ++r) acc[mi][j][r] += bias;
  }
#pragma unroll
  for (int mi = 0; mi < 2; ++mi)
#pragma unroll
    for (int r = 0; r < 4; ++r) {
      float s1 = 0.f, s2 = 0.f;
#pragma unroll
      for (int j = 0; j < 8; ++j) { float x = acc[mi][j][r]; s1 += x; s2 += x * x; }
#pragma unroll
      for (int off = 1; off < 16; off <<= 1) { s1 += __shfl_xor(s1, off); s2 += __shfl_xor(s2, off); }
      if (ml == 0) red[(mi * 16 + 4 * qd + r) * 4 + wv] = make_float2(s1, s2);
    }
  barrier_lds();  // red visible; all waves past their As a-frag reads
  if (tid < 32) {
    float S1 = 0.f, S2 = 0.f;
#pragma unroll
    for (int w = 0; w < 4; ++w) { float2 v = red[tid * 4 + w]; S1 += v.x; S2 += v.y; }
    float mean = S1 * (1.f / 512.f);
    float var = S2 * (1.f / 512.f) - mean * mean;
    stat[tid * 2] = mean;
    stat[tid * 2 + 1] = rsqrtf(var + 1e-5f);
  }
  barrier_lds();
#pragma unroll
  for (int mi = 0; mi < 2; ++mi)
#pragma unroll
    for (int r = 0; r < 4; ++r) {
      int row = mi * 16 + 4 * qd + r;
      float mean = stat[row * 2], rstd = stat[row * 2 + 1];
#pragma unroll
      for (int j = 0; j < 8; ++j) {
        int n = (8 * wv + j) * 16 + ml;
        float x = (acc[mi][j][r] - mean) * rstd * bf2f(Ps[pg * 512 + n]) + bf2f(Ps[pbe * 512 + n]);
        x = x > 0.f ? x : 0.01f * x;
        As[a_addr(row, n)] = f2bf(x);
      }
    }
  barrier_lds();  // As writes visible
}

// RK4 stage: k = acc + bout; h fp32 regs, ksum packed bf16 pairs; writes y
// into As; on the final stage also writes h_ode to Yb.
static __device__ __forceinline__ void stage_epi32(floatx4 (&acc)[2][8], float (&h)[2][8][4],
                                                   unsigned int (&ks)[2][8][2], unsigned short* As,
                                                   unsigned short* Yb, size_t m0,
                                                   const unsigned short* Ps, int stg, bool last,
                                                   int wv, int lane) {
  const int ml = lane & 15, qd = lane >> 4;
  barrier_lds();  // K-loop has no barriers: ensure all waves done reading As
#pragma unroll
  for (int mi = 0; mi < 2; ++mi)
#pragma unroll
    for (int j = 0; j < 8; ++j) {
      int n = (8 * wv + j) * 16 + ml;
      float bias = bf2f(Ps[7 * 512 + n]);
#pragma unroll
      for (int rp = 0; rp < 2; ++rp) {
        float kv0 = acc[mi][j][2 * rp] + bias;
        float kv1 = acc[mi][j][2 * rp + 1] + bias;
        unsigned int pk = ks[mi][j][rp];
        float s0 = bf2f((unsigned short)(pk & 0xffffu));
        float s1 = bf2f((unsigned short)(pk >> 16));
        float h0 = h[mi][j][2 * rp], h1 = h[mi][j][2 * rp + 1];
        float y0, y1;
        if (stg == 0)      { s0 = kv0;        s1 = kv1;        y0 = h0 + 0.125f * kv0; y1 = h1 + 0.125f * kv1; }
        else if (stg == 1) { s0 += 2.f * kv0; s1 += 2.f * kv1; y0 = h0 + 0.125f * kv0; y1 = h1 + 0.125f * kv1; }
        else if (stg == 2) { s0 += 2.f * kv0; s1 += 2.f * kv1; y0 = h0 + 0.25f * kv0;  y1 = h1 + 0.25f * kv1; }
        else {
          h0 += (1.f / 24.f) * (s0 + kv0);  // dt/6, dt=0.25
          h1 += (1.f / 24.f) * (s1 + kv1);
          h[mi][j][2 * rp] = h0; h[mi][j][2 * rp + 1] = h1;
          y0 = h0; y1 = h1;
        }
        ks[mi][j][rp] = (unsigned int)f2bf(s0) | ((unsigned int)f2bf(s1) << 16);
        int row = mi * 16 + 4 * qd + 2 * rp;
        As[a_addr(row, n)] = f2bf(y0);
        As[a_addr(row + 1, n)] = f2bf(y1);
        if (last && stg == 3) {
          Yb[(m0 + row) * 512 + n] = f2bf(y0);
          Yb[(m0 + row + 1) * 512 + n] = f2bf(y1);
        }
      }
    }
  barrier_lds();  // As writes visible
}

__global__ __launch_bounds__(256) void ode_mega(
    unsigned short* Yb, const unsigned short* __restrict__ W1t,
    const unsigned short* __restrict__ W2t, const unsigned short* __restrict__ Wot,
    const float* __restrict__ b1, const float* __restrict__ tr, const float* __restrict__ g1,
    const float* __restrict__ be1, const float* __restrict__ b2, const float* __restrict__ g2,
    const float* __restrict__ be2, const float* __restrict__ bo) {
  __shared__ __align__(16) unsigned short As[16384];  // 32KB tiled A (32 rows)
  __shared__ __align__(16) unsigned short Ps[4096];   // 8KB params
  __shared__ float2 red[128];                         // 1KB: 32 rows x 4 waves
  __shared__ float stat[64];                          // 256B -> ~41.5KB, 2 blocks/CU

  const int tid = threadIdx.x;
  const int lane = tid & 63;
  const int wv = tid >> 6;  // 0..3
  const int ml = lane & 15;
  const int qd = lane >> 4;
  const size_t m0 = (size_t)blockIdx.x * 32;

  // start weight prefetch immediately: W1 groups 0..3
  bf16x8 bb[4][4];
#pragma unroll
  for (int g = 0; g < 4; ++g) bload4(W1t, g, wv, lane, bb[g]);

  {
    const float* srcs[8] = {b1, tr, g1, be1, b2, g2, be2, bo};
#pragma unroll
    for (int v = 0; v < 8; ++v) {
      Ps[v * 512 + tid] = f2bf(srcs[v][tid]);
      Ps[v * 512 + 256 + tid] = f2bf(srcs[v][256 + tid]);
    }
  }
  // stage As: thread owns row r = tid>>3, chunks c = i*8 + (tid&7)
  {
    int r = tid >> 3;  // 0..31
#pragma unroll
    for (int i = 0; i < 8; ++i) {
      int c = i * 8 + (tid & 7);
      uint4 v = *(const uint4*)(Yb + (m0 + r) * 512 + c * 8);
      int dst = (((r >> 4) * 16 + (c >> 2)) * 4 + (c & 3)) * 128 + (r & 15) * 8;
      *(uint4*)(As + dst) = v;
    }
  }
  barrier_lds();

  float h[2][8][4];          // fp32 ODE state, MFMA C-layout
  unsigned int ks[2][8][2];  // RK4 ksum, packed bf16 pairs
#pragma unroll
  for (int mi = 0; mi < 2; ++mi)
#pragma unroll
    for (int j = 0; j < 8; ++j) {
      ks[mi][j][0] = 0u; ks[mi][j][1] = 0u;
      int n = (8 * wv + j) * 16 + ml;
#pragma unroll
      for (int r = 0; r < 4; ++r) h[mi][j][r] = bf2f(As[a_addr(mi * 16 + 4 * qd + r, n)]);
    }

  for (int e = 0; e < 16; ++e) {  // 4 RK4 steps x 4 stages
    int stg = e & 3;
    float tval = 0.25f * (float)(e >> 2) + ((stg == 3) ? 0.25f : (stg ? 0.125f : 0.f));
    floatx4 acc[2][8];
    gemm32(W1t, W2t, As, wv, lane, bb, acc);
    ln_epi32(acc, As, Ps, 0, 2, 3, true, tval, wv, lane, tid, red, stat);
    gemm32(W2t, Wot, As, wv, lane, bb, acc);
    ln_epi32(acc, As, Ps, 4, 5, 6, false, 0.f, wv, lane, tid, red, stat);
    gemm32(Wot, W1t, As, wv, lane, bb, acc);  // preloads next eval's W1
    stage_epi32(acc, h, ks, As, Yb, m0, Ps, stg, e == 15, wv, lane);
  }
}

// ---------------------------------------------------------------------------
// GRU step (unchanged): gi = y_t @ W_ih, gh = h_prev @ W_hh, gates.
// grid (32, 8): 32 rows x 64 gate-cols per block, 4 waves.
// ---------------------------------------------------------------------------
__global__ __launch_bounds__(256) void gru_step(
    const unsigned short* __restrict__ Yt, const float* __restrict__ hprev,
    float* __restrict__ hnew, const unsigned short* __restrict__ Wiht,
    const unsigned short* __restrict__ Whht, const float* __restrict__ bih,
    const float* __restrict__ bhh) {
  __shared__ __align__(16) unsigned short Ay[32 * BP];
  __shared__ __align__(16) unsigned short Ah[32 * BP];
  __shared__ __align__(16) unsigned short Bg[6 * 64 * BP];
  const int tid = threadIdx.x, lane = tid & 63, wv = tid >> 6;
  const int ml = lane & 15, qd = lane >> 4;
  const int m0 = blockIdx.x * 32;
  const int j0 = blockIdx.y * 64;

  floatx4 acc[2][6];
#pragma unroll
  for (int mi = 0; mi < 2; ++mi)
#pragma unroll
    for (int g = 0; g < 6; ++g) acc[mi][g] = 0.f;

  for (int kk = 0; kk < 16; ++kk) {
    __syncthreads();
#pragma unroll
    for (int c = 0; c < 7; ++c) {
      int id = c * 256 + tid;
      if (id < 128) {
        int r = id >> 2, kc = id & 3;
        *(uint4*)(Ay + r * BP + kc * 8) =
            *(const uint4*)(Yt + (size_t)(m0 + r) * 512 + kk * 32 + kc * 8);
      } else if (id < 256) {
        int id2 = id - 128;
        int r = id2 >> 2, kc = id2 & 3;
        const float* s = hprev + (size_t)(m0 + r) * 512 + kk * 32 + kc * 8;
        unsigned short o[8] __attribute__((aligned(16)));
#pragma unroll
        for (int j = 0; j < 8; ++j) o[j] = f2bf(s[j]);
        *(uint4*)(Ah + r * BP + kc * 8) = *(const uint4*)o;
      } else {
        int id2 = id - 256;
        int g = id2 >> 8;
        int rem = id2 & 255;
        int r = rem >> 2, kc = rem & 3;
        const unsigned short* mat = (g < 3) ? Wiht : Whht;
        int gate = (g < 3) ? g : (g - 3);
        *(uint4*)(Bg + g * (64 * BP) + r * BP + kc * 8) =
            *(const uint4*)(mat + (size_t)(gate * 512 + j0 + r) * 512 + kk * 32 + kc * 8);
      }
    }
    __syncthreads();
    bf16x8 ay[2], ah[2];
#pragma unroll
    for (int mi = 0; mi < 2; ++mi) {
      ay[mi] = *(const bf16x8*)&Ay[(16 * mi + ml) * BP + qd * 8];
      ah[mi] = *(const bf16x8*)&Ah[(16 * mi + ml) * BP + qd * 8];
    }
#pragma unroll
    for (int g = 0; g < 6; ++g) {
      bf16x8 b = *(const bf16x8*)&Bg[g * (64 * BP) + (16 * wv + ml) * BP + qd * 8];
#pragma unroll
      for (int mi = 0; mi < 2; ++mi)
        acc[mi][g] = __builtin_amdgcn_mfma_f32_16x16x32_bf16((g < 3) ? ay[mi] : ah[mi], b,
                                                             acc[mi][g], 0, 0, 0);
    }
  }
  int j = j0 + 16 * wv + ml;
  float bi_r = bih[j], bi_z = bih[512 + j], bi_n = bih[1024 + j];
  float bh_r = bhh[j], bh_z = bhh[512 + j], bh_n = bhh[1024 + j];
#pragma unroll
  for (int mi = 0; mi < 2; ++mi)
#pragma unroll
    for (int r = 0; r < 4; ++r) {
      size_t row = (size_t)(m0 + 16 * mi + 4 * qd + r);
      float rg = acc[mi][0][r] + bi_r + acc[mi][3][r] + bh_r;
      rg = 1.f / (1.f + __expf(-rg));
      float zg = acc[mi][1][r] + bi_z + acc[mi][4][r] + bh_z;
      zg = 1.f / (1.f + __expf(-zg));
      float ng = tanhf(acc[mi][2][r] + bi_n + rg * (acc[mi][5][r] + bh_n));
      float hp = hprev[row * 512 + j];
      hnew[row * 512 + j] = (1.f - zg) * ng + zg * hp;
    }
}

__global__ void zero_h(float* hf) {
  int i = blockIdx.x * 256 + threadIdx.x;
  hf[i] = 0.f;
}

// ---------------------------------------------------------------------------
extern "C" void kernel_launch(void* const* d_in, const int* in_sizes, int n_in,
                              void* d_out, int out_size, void* d_ws, size_t ws_size,
                              hipStream_t stream) {
  (void)in_sizes; (void)n_in; (void)out_size; (void)ws_size;
  const float* xs    = (const float*)d_in[0];
  const float* obsW  = (const float*)d_in[1];
  const float* obsb  = (const float*)d_in[2];
  const float* obsg  = (const float*)d_in[3];
  const float* obsbe = (const float*)d_in[4];
  const float* W1    = (const float*)d_in[5];
  const float* b1    = (const float*)d_in[6];
  const float* g1    = (const float*)d_in[7];
  const float* be1   = (const float*)d_in[8];
  const float* W2    = (const float*)d_in[9];
  const float* b2    = (const float*)d_in[10];
  const float* g2    = (const float*)d_in[11];
  const float* be2   = (const float*)d_in[12];
  const float* Wo    = (const float*)d_in[13];
  const float* bo    = (const float*)d_in[14];
  const float* Wih   = (const float*)d_in[15];
  const float* bih   = (const float*)d_in[16];
  const float* Whh   = (const float*)d_in[17];
  const float* bhh   = (const float*)d_in[18];

  char* p = (char*)d_ws;
  auto take = [&](size_t bytes) { char* q = p; p += (bytes + 255) & ~(size_t)255; return q; };
  unsigned short* W1t  = (unsigned short*)take((size_t)512 * 512 * 2);
  unsigned short* W2t  = (unsigned short*)take((size_t)512 * 512 * 2);
  unsigned short* Wot  = (unsigned short*)take((size_t)512 * 512 * 2);
  unsigned short* Wiht = (unsigned short*)take((size_t)1536 * 512 * 2);
  unsigned short* Whht = (unsigned short*)take((size_t)1536 * 512 * 2);
  float* hf0 = (float*)take((size_t)1024 * 512 * 4);
  float* hf1 = (float*)take((size_t)1024 * 512 * 4);
  unsigned short* Yb = (unsigned short*)take((size_t)65536 * 512 * 2);

  dim3 tb(32, 8);
  tile_weight<<<128, 256, 0, stream>>>(W1, W1t);  // first 512 of 513 rows
  tile_weight<<<128, 256, 0, stream>>>(W2, W2t);
  tile_weight<<<128, 256, 0, stream>>>(Wo, Wot);
  transpose_f2b<<<dim3(48, 16), tb, 0, stream>>>(Wih, Wiht, 512, 1536);
  transpose_f2b<<<dim3(48, 16), tb, 0, stream>>>(Whh, Whht, 512, 1536);

  obs_embed<<<16384, 256, 0, stream>>>(xs, obsW, obsb, obsg, obsbe, Yb);

  // tr = W1 row 512 (time row), folded into layer-1 bias per eval.
  ode_mega<<<2048, 256, 0, stream>>>(Yb, W1t, W2t, Wot, b1, W1 + 512 * 512, g1, be1, b2, g2,
                                     be2, bo);

  zero_h<<<2048, 256, 0, stream>>>(hf0);
  float* hf[2] = {hf0, hf1};
  for (int t = 0; t < 64; ++t) {
    int s = t & 1, d = s ^ 1;
    float* hn = (t == 63) ? (float*)d_out : hf[d];
    gru_step<<<dim3(32, 8), 256, 0, stream>>>(Yb + (size_t)t * 1024 * 512, hf[s], hn, Wiht, Whht,
                                              bih, bhh);
  }
}